// Round 10
// baseline (536.932 us; speedup 1.0000x reference)
//
#include <hip/hip_runtime.h>

typedef __attribute__((ext_vector_type(4))) float f32x4;
typedef __attribute__((ext_vector_type(8))) short bf16x8;
typedef unsigned short u16;

#define LNEPS 1e-3f
#define ATTN_EPS 1e-8f
#define SCALE 0.044194173824159216f  // 512^-0.5

__device__ __forceinline__ u16 f2bf(float f) {
  union { float f; unsigned u; } v; v.f = f;
  unsigned r = v.u + 0x7fffu + ((v.u >> 16) & 1u);
  return (u16)(r >> 16);
}
__device__ __forceinline__ float bf2f(unsigned u) {
  union { float f; unsigned u; } v; v.u = (u & 0xffffu) << 16; return v.f;
}
__device__ __forceinline__ f32x4 mfma16(bf16x8 a, bf16x8 b, f32x4 c) {
  return __builtin_amdgcn_mfma_f32_16x16x32_bf16(a, b, c, 0, 0, 0);
}
__device__ __forceinline__ unsigned pk2(float a, float b) {
  return (unsigned)f2bf(a) | ((unsigned)f2bf(b) << 16);
}

// ---------------- weight convert / transpose to bf16 ----------------
__global__ void cvt_kernel(const float* __restrict__ src, u16* __restrict__ dst,
                           int rows, int cols, int trans) {
  const int total = rows * cols;
  for (int i = blockIdx.x * blockDim.x + threadIdx.x; i < total;
       i += gridDim.x * blockDim.x) {
    const int r = i / cols, c = i - r * cols;
    const u16 v = f2bf(src[i]);
    dst[trans ? (c * rows + r) : i] = v;
  }
}

// k-slab layout for GEMM B: dst[ks][c+coff][q] = src[(ks*32+q)*128 + c]
__global__ void cvt_ktile(const float* __restrict__ src, u16* __restrict__ dst,
                          int coff) {
  const int i = blockIdx.x * blockDim.x + threadIdx.x;  // over 512*128
  if (i < 512 * 128) {
    const int k = i >> 7, c = i & 127;
    dst[(k >> 5) * 8192 + (c + coff) * 32 + (k & 31)] = f2bf(src[i]);
  }
}

// ---------------- K1: LN(features) -> k,v projections ----------------
// grid 16384 blocks x 256 thr (4 waves). Block: 16 rows x 256 cols, K=512.
// 16 KB LDS + launch_bounds(256,8) -> 8 blocks/CU = 32 waves/CU (max):
// maximal cross-block phase overlap; 4 rows/wave halves serial chains.
// Phase 1 is the r4/r7/r9-PROVEN butterfly+LN-in-regs pattern.
__global__ __launch_bounds__(256, 8) void k1_lnproj(
    const float* __restrict__ feats, const float* __restrict__ lng,
    const float* __restrict__ lnb, const u16* __restrict__ Wcat,
    const float* __restrict__ bk, const float* __restrict__ bv,
    u16* __restrict__ kbuf, u16* __restrict__ vt) {
  __shared__ alignas(16) union {
    u16 a[16 * 512];                                    // 16384 B (GEMM A)
    struct { u16 kq[16 * 136]; float c[128 * 20]; } e;  // 4352+10240 B
  } sm;
  const int tid = threadIdx.x;
  const int wave = tid >> 6, lane = tid & 63;
  const int lq = lane >> 4, lm = lane & 15;
  const long long row0 = (long long)blockIdx.x * 16;

  // LN params for this lane's 8 columns (uniform across rows)
  const float4 g0 = *(const float4*)&lng[lane * 8];
  const float4 g1 = *(const float4*)&lng[lane * 8 + 4];
  const float4 bb0 = *(const float4*)&lnb[lane * 8];
  const float4 bb1 = *(const float4*)&lnb[lane * 8 + 4];

  // ---- phase 1: load 4 rows/wave + butterfly stats + LN in regs ----
  {
    const float* base = feats + (row0 + wave * 4) * 512 + lane * 8;
    float4 x0[4], x1[4];
#pragma unroll
    for (int i = 0; i < 4; ++i) {
      x0[i] = ((const float4*)(base + i * 512))[0];
      x1[i] = ((const float4*)(base + i * 512))[1];
    }
#pragma unroll
    for (int i = 0; i < 4; ++i) {
      const int r = wave * 4 + i;
      float s = (x0[i].x + x0[i].y) + (x0[i].z + x0[i].w) +
                (x1[i].x + x1[i].y) + (x1[i].z + x1[i].w);
      float q = x0[i].x * x0[i].x + x0[i].y * x0[i].y + x0[i].z * x0[i].z +
                x0[i].w * x0[i].w + x1[i].x * x1[i].x + x1[i].y * x1[i].y +
                x1[i].z * x1[i].z + x1[i].w * x1[i].w;
#pragma unroll
      for (int m = 1; m < 64; m <<= 1) {
        s += __shfl_xor(s, m);
        q += __shfl_xor(q, m);
      }
      const float mu = s * (1.f / 512.f);
      const float rstd = rsqrtf(q * (1.f / 512.f) - mu * mu + LNEPS);
      const float y0 = (x0[i].x - mu) * rstd * g0.x + bb0.x;
      const float y1 = (x0[i].y - mu) * rstd * g0.y + bb0.y;
      const float y2 = (x0[i].z - mu) * rstd * g0.z + bb0.z;
      const float y3 = (x0[i].w - mu) * rstd * g0.w + bb0.w;
      const float y4 = (x1[i].x - mu) * rstd * g1.x + bb1.x;
      const float y5 = (x1[i].y - mu) * rstd * g1.y + bb1.y;
      const float y6 = (x1[i].z - mu) * rstd * g1.z + bb1.z;
      const float y7 = (x1[i].w - mu) * rstd * g1.w + bb1.w;
      uint4 w;
      w.x = pk2(y0, y1);
      w.y = pk2(y2, y3);
      w.z = pk2(y4, y5);
      w.w = pk2(y6, y7);
      *(uint4*)((char*)sm.a + r * 1024 + ((lane * 16) ^ ((r & 7) << 4))) = w;
    }
  }
  __syncthreads();

  // ---- GEMM: wave = col-quarter cq; rows 0..15 (1 m-tile) ----
  const int cq = wave;
  f32x4 acc[4];
  {
    const f32x4 z4 = {0.f, 0.f, 0.f, 0.f};
#pragma unroll
    for (int n = 0; n < 4; ++n) acc[n] = z4;
  }
  const u16* wb = Wcat + (cq * 64 + lm) * 32 + lq * 8;  // k-slab base
#pragma unroll 4
  for (int ks = 0; ks < 16; ++ks) {
    const int row = lm;
    const bf16x8 a = *(const bf16x8*)((const char*)sm.a + row * 1024 +
                                      ((ks * 64 + lq * 16) ^ ((row & 7) << 4)));
    bf16x8 b[4];
#pragma unroll
    for (int nt = 0; nt < 4; ++nt)
      b[nt] = *(const bf16x8*)&wb[ks * 8192 + nt * 512];
#pragma unroll
    for (int nt = 0; nt < 4; ++nt)
      acc[nt] = mfma16(a, b[nt], acc[nt]);
  }
  __syncthreads();  // A-tile dead; union becomes epilogue staging

  // ---- epilogue staging: k (bf16) and v (fp32, transposed) into LDS ----
  if (cq < 2) {
#pragma unroll
    for (int nt = 0; nt < 4; ++nt) {
      const int col = cq * 64 + nt * 16 + lm;
      const float bias = bk[col];
#pragma unroll
      for (int r = 0; r < 4; ++r) {
        const int row = lq * 4 + r;
        sm.e.kq[row * 136 + col] = f2bf(acc[nt][r] + bias);
      }
    }
  } else {
#pragma unroll
    for (int nt = 0; nt < 4; ++nt) {
      const int d = (cq - 2) * 64 + nt * 16 + lm;
      const float bias = bv[d];
#pragma unroll
      for (int r = 0; r < 4; ++r) {
        const int row = lq * 4 + r;
        sm.e.c[d * 20 + row] = acc[nt][r] + bias;
      }
    }
  }
  __syncthreads();

  const long long bidx = row0 >> 12;
  const int nbase = (int)(row0 & 4095);
  // ---- pack k: 16 rows x 128 cols, coalesced 16B stores (all 256 thr) ----
  {
    const int row = tid >> 4, c0 = (tid & 15) * 8;
    const u16* sp = &sm.e.kq[row * 136 + c0];
    u16* dst = kbuf + (row0 + row) * 128 + c0;
    *(uint4*)(dst) = *(const uint4*)(sp);
  }
  // ---- pack v^T: [d][N] bf16 (all 256 thr) ----
  {
    const int d = tid >> 1, nh = (tid & 1) * 8;
    const float* cp = &sm.e.c[d * 20 + nh];
    u16* dst = vt + (bidx * 128 + d) * 4096 + nbase + nh;
    uint4 p;
    p.x = pk2(cp[0], cp[1]);
    p.y = pk2(cp[2], cp[3]);
    p.z = pk2(cp[4], cp[5]);
    p.w = pk2(cp[6], cp[7]);
    *(uint4*)(dst) = p;
  }
}

// ---------------- K3: q-proj + dots + slot-softmax + P@v partials ----------
// grid 512 blocks (64 batches x 8 chunks), 256 thr. Wave handles 128 tokens.
__global__ __launch_bounds__(256) void k3_attn(
    const float* __restrict__ slots_in, const int* __restrict__ is_first, int iter,
    const float* __restrict__ lsg, const float* __restrict__ lsb,
    const u16* __restrict__ Wqt, const float* __restrict__ bq,
    const u16* __restrict__ kbuf, const u16* __restrict__ vt,
    float* __restrict__ updp, float* __restrict__ rsp) {
  const int ni = (*is_first) ? 3 : 2;
  if (iter >= ni) return;
  __shared__ alignas(16) u16 slns[16 * 136];
  __shared__ alignas(16) u16 qlds[16 * 136];
  __shared__ alignas(16) u16 plds[4][640];
  __shared__ alignas(16) float ures[4][16 * 128];
  __shared__ float rres[4][16];
  const int tid = threadIdx.x;
  const int wave = tid >> 6, lane = tid & 63;
  const int lq = lane >> 4, lm = lane & 15;
  const int b = blockIdx.x >> 3, chunk = blockIdx.x & 7;

  // LN(slots) by wave 0
  if (wave == 0) {
    const int s = lane >> 2, cc = (lane & 3) * 32;
    const float* sp = slots_in + ((long long)b * 16 + s) * 128 + cc;
    float x[32];
    float sum = 0.f, sq = 0.f;
#pragma unroll
    for (int j = 0; j < 32; ++j) { x[j] = sp[j]; sum += x[j]; sq += x[j] * x[j]; }
    sum += __shfl_xor(sum, 1); sum += __shfl_xor(sum, 2);
    sq  += __shfl_xor(sq, 1);  sq  += __shfl_xor(sq, 2);
    const float mu = sum * (1.f / 128.f);
    const float rstd = rsqrtf(sq * (1.f / 128.f) - mu * mu + LNEPS);
#pragma unroll
    for (int j = 0; j < 32; ++j) {
      const int c = cc + j;
      slns[s * 136 + c] = f2bf((x[j] - mu) * rstd * lsg[c] + lsb[c]);
    }
  }
  __syncthreads();
  // q = LN(slots) @ Wq + bq ; wave computes cols [wave*32, wave*32+32)
  {
    f32x4 qa0 = {0.f, 0.f, 0.f, 0.f}, qa1 = {0.f, 0.f, 0.f, 0.f};
#pragma unroll
    for (int ks = 0; ks < 4; ++ks) {
      const bf16x8 af = *(const bf16x8*)&slns[lm * 136 + ks * 32 + lq * 8];
      const bf16x8 b0 = *(const bf16x8*)&Wqt[(wave * 32 + lm) * 128 + ks * 32 + lq * 8];
      const bf16x8 b1 = *(const bf16x8*)&Wqt[(wave * 32 + 16 + lm) * 128 + ks * 32 + lq * 8];
      qa0 = mfma16(af, b0, qa0);
      qa1 = mfma16(af, b1, qa1);
    }
#pragma unroll
    for (int r = 0; r < 4; ++r) {
      const int s = lq * 4 + r;
      const int c0 = wave * 32 + lm, c1 = c0 + 16;
      qlds[s * 136 + c0] = f2bf(qa0[r] + bq[c0]);
      qlds[s * 136 + c1] = f2bf(qa1[r] + bq[c1]);
    }
  }
  __syncthreads();

  bf16x8 qf[4];
#pragma unroll
  for (int ks = 0; ks < 4; ++ks)
    qf[ks] = *(const bf16x8*)&qlds[lm * 136 + ks * 32 + lq * 8];

  float rs0 = 0.f, rs1 = 0.f, rs2 = 0.f, rs3 = 0.f;
  const f32x4 z4 = {0.f, 0.f, 0.f, 0.f};
  f32x4 uacc[8];
#pragma unroll
  for (int i = 0; i < 8; ++i) uacc[i] = z4;
  u16* pw = plds[wave];
  const int n0w = chunk * 512 + wave * 128;
  const u16* kb = kbuf + (long long)b * 4096 * 128;
  const u16* vb = vt + (long long)b * 128 * 4096;

  for (int g = 0; g < 4; ++g) {
    const int nb = n0w + g * 32;
#pragma unroll
    for (int sub = 0; sub < 2; ++sub) {
      f32x4 dot = z4;
      const u16* kr = kb + (long long)(nb + sub * 16 + lm) * 128 + lq * 8;
#pragma unroll
      for (int ks = 0; ks < 4; ++ks)
        dot = mfma16(qf[ks], *(const bf16x8*)&kr[ks * 32], dot);
      const float d0 = dot[0] * SCALE, d1 = dot[1] * SCALE;
      const float d2 = dot[2] * SCALE, d3 = dot[3] * SCALE;
      float m = fmaxf(fmaxf(d0, d1), fmaxf(d2, d3));
      m = fmaxf(m, __shfl_xor(m, 16));
      m = fmaxf(m, __shfl_xor(m, 32));
      const float e0 = __expf(d0 - m), e1 = __expf(d1 - m);
      const float e2 = __expf(d2 - m), e3 = __expf(d3 - m);
      float ss = e0 + e1 + e2 + e3;
      ss += __shfl_xor(ss, 16);
      ss += __shfl_xor(ss, 32);
      const float inv = 1.f / ss;
      const float p0 = e0 * inv + ATTN_EPS, p1 = e1 * inv + ATTN_EPS;
      const float p2 = e2 * inv + ATTN_EPS, p3 = e3 * inv + ATTN_EPS;
      rs0 += p0; rs1 += p1; rs2 += p2; rs3 += p3;
      const int nc = sub * 16 + lm;
      pw[(lq * 4 + 0) * 40 + nc] = f2bf(p0);
      pw[(lq * 4 + 1) * 40 + nc] = f2bf(p1);
      pw[(lq * 4 + 2) * 40 + nc] = f2bf(p2);
      pw[(lq * 4 + 3) * 40 + nc] = f2bf(p3);
    }
    const bf16x8 pa = *(const bf16x8*)&pw[lm * 40 + lq * 8];
    const u16* vr = vb + (long long)lm * 4096 + nb + lq * 8;
#pragma unroll
    for (int dt = 0; dt < 8; ++dt)
      uacc[dt] = mfma16(pa, *(const bf16x8*)&vr[(long long)dt * 16 * 4096], uacc[dt]);
  }
  // rowsum reduce across the 16 lanes of each quarter
#pragma unroll
  for (int msk = 1; msk < 16; msk <<= 1) {
    rs0 += __shfl_xor(rs0, msk); rs1 += __shfl_xor(rs1, msk);
    rs2 += __shfl_xor(rs2, msk); rs3 += __shfl_xor(rs3, msk);
  }
#pragma unroll
  for (int dt = 0; dt < 8; ++dt)
#pragma unroll
    for (int r = 0; r < 4; ++r)
      ures[wave][(lq * 4 + r) * 128 + dt * 16 + lm] = uacc[dt][r];
  if (lm == 0) {
    rres[wave][lq * 4 + 0] = rs0; rres[wave][lq * 4 + 1] = rs1;
    rres[wave][lq * 4 + 2] = rs2; rres[wave][lq * 4 + 3] = rs3;
  }
  __syncthreads();
  {
    const int e0 = tid * 8;
    float* dst = updp + (long long)(b * 8 + chunk) * 2048 + e0;
#pragma unroll
    for (int e = 0; e < 8; ++e)
      dst[e] = ures[0][e0 + e] + ures[1][e0 + e] + ures[2][e0 + e] + ures[3][e0 + e];
  }
  if (tid < 16)
    rsp[(b * 8 + chunk) * 16 + tid] =
        rres[0][tid] + rres[1][tid] + rres[2][tid] + rres[3][tid];
}

// ---------------- K4: reduce partials + GRU + MLP -> new slots -------------
// grid 64 blocks (batch), 256 thr.
__global__ __launch_bounds__(256) void k4_update(
    const float* __restrict__ slots_in, const int* __restrict__ is_first, int iter,
    const float* __restrict__ updp, const float* __restrict__ rsp,
    const u16* __restrict__ Wih, const u16* __restrict__ Whh,
    const float* __restrict__ bih, const float* __restrict__ bhh,
    const float* __restrict__ lmg, const float* __restrict__ lmb,
    const u16* __restrict__ W1t, const float* __restrict__ b1,
    const u16* __restrict__ W2t, const float* __restrict__ b2,
    float* __restrict__ slots_out, float* __restrict__ dout) {
  const int ni = (*is_first) ? 3 : 2;
  if (iter >= ni) return;
  const bool last = (iter == ni - 1);
  __shared__ float g_ih[16 * 392];
  __shared__ float g_hh[16 * 392];
  __shared__ alignas(16) float hsp[16 * 128];
  __shared__ float rsum[16];
  __shared__ alignas(16) u16 ubf[16 * 136];
  __shared__ alignas(16) u16 xbf[16 * 136];
  __shared__ alignas(16) u16 hidbf[16 * 520];
  const int tid = threadIdx.x;
  const int wave = tid >> 6, lane = tid & 63;
  const int lq = lane >> 4, lm = lane & 15;
  const int b = blockIdx.x;
  const int es = tid >> 4;         // slot row for this thread's 8 elems
  const int ej = (tid & 15) * 8;   // col start

  // slots_prev -> hsp (fp32) and xbf (bf16)
  {
    const float* sp = slots_in + (long long)b * 2048 + tid * 8;
    const float4 a = ((const float4*)sp)[0], c = ((const float4*)sp)[1];
    *(float4*)&hsp[tid * 8] = a;
    *(float4*)&hsp[tid * 8 + 4] = c;
    uint4 p;
    p.x = pk2(a.x, a.y);
    p.y = pk2(a.z, a.w);
    p.z = pk2(c.x, c.y);
    p.w = pk2(c.z, c.w);
    *(uint4*)&xbf[es * 136 + ej] = p;
  }
  if (tid < 16) {
    float s = 0.f;
    for (int p = 0; p < 8; ++p) s += rsp[(b * 8 + p) * 16 + tid];
    rsum[tid] = s;
  }
  __syncthreads();
  // reduce updates partials, normalize by rowsum -> ubf (bf16)
  {
    float acc[8];
#pragma unroll
    for (int e = 0; e < 8; ++e) acc[e] = 0.f;
    for (int p = 0; p < 8; ++p) {
      const float* src = updp + (long long)(b * 8 + p) * 2048 + tid * 8;
      const float4 x = ((const float4*)src)[0], y = ((const float4*)src)[1];
      acc[0] += x.x; acc[1] += x.y; acc[2] += x.z; acc[3] += x.w;
      acc[4] += y.x; acc[5] += y.y; acc[6] += y.z; acc[7] += y.w;
    }
    const float inv = 1.f / rsum[es];
    uint4 p;
    p.x = pk2(acc[0] * inv, acc[1] * inv);
    p.y = pk2(acc[2] * inv, acc[3] * inv);
    p.z = pk2(acc[4] * inv, acc[5] * inv);
    p.w = pk2(acc[6] * inv, acc[7] * inv);
    *(uint4*)&ubf[es * 136 + ej] = p;
  }
  __syncthreads();
  // gi = u @ Wih^T + bih ; gh = h @ Whh^T + bhh  (wave: cols wave*96..+96)
  {
    bf16x8 ua[4], ha[4];
#pragma unroll
    for (int ks = 0; ks < 4; ++ks) {
      ua[ks] = *(const bf16x8*)&ubf[lm * 136 + ks * 32 + lq * 8];
      ha[ks] = *(const bf16x8*)&xbf[lm * 136 + ks * 32 + lq * 8];
    }
    const f32x4 z4 = {0.f, 0.f, 0.f, 0.f};
    f32x4 gi[6], gh[6];
#pragma unroll
    for (int t = 0; t < 6; ++t) { gi[t] = z4; gh[t] = z4; }
#pragma unroll
    for (int ks = 0; ks < 4; ++ks)
#pragma unroll
      for (int t = 0; t < 6; ++t) {
        const int col = wave * 96 + t * 16 + lm;
        gi[t] = mfma16(ua[ks], *(const bf16x8*)&Wih[(long long)col * 128 + ks * 32 + lq * 8], gi[t]);
        gh[t] = mfma16(ha[ks], *(const bf16x8*)&Whh[(long long)col * 128 + ks * 32 + lq * 8], gh[t]);
      }
#pragma unroll
    for (int t = 0; t < 6; ++t)
#pragma unroll
      for (int r = 0; r < 4; ++r) {
        const int col = wave * 96 + t * 16 + lm, s = lq * 4 + r;
        g_ih[s * 392 + col] = gi[t][r] + bih[col];
        g_hh[s * 392 + col] = gh[t][r] + bhh[col];
      }
  }
  __syncthreads();
  // gates (elementwise), h overwrites hsp
  {
#pragma unroll
    for (int e = 0; e < 8; ++e) {
      const int j = ej + e;
      const float sr = g_ih[es * 392 + j] + g_hh[es * 392 + j];
      const float sz = g_ih[es * 392 + 128 + j] + g_hh[es * 392 + 128 + j];
      const float r = 1.f / (1.f + __expf(-sr));
      const float z = 1.f / (1.f + __expf(-sz));
      const float n = tanhf(g_ih[es * 392 + 256 + j] + r * g_hh[es * 392 + 256 + j]);
      hsp[es * 128 + j] = (1.f - z) * n + z * hsp[es * 128 + j];
    }
  }
  __syncthreads();
  // LN(h) -> xbf (wave 0)
  if (wave == 0) {
    const int s = lane >> 2, cc = (lane & 3) * 32;
    float x[32];
    float sum = 0.f, sq = 0.f;
#pragma unroll
    for (int j = 0; j < 32; ++j) {
      x[j] = hsp[s * 128 + cc + j]; sum += x[j]; sq += x[j] * x[j];
    }
    sum += __shfl_xor(sum, 1); sum += __shfl_xor(sum, 2);
    sq  += __shfl_xor(sq, 1);  sq  += __shfl_xor(sq, 2);
    const float mu = sum * (1.f / 128.f);
    const float rstd = rsqrtf(sq * (1.f / 128.f) - mu * mu + LNEPS);
#pragma unroll
    for (int j = 0; j < 32; ++j) {
      const int c = cc + j;
      xbf[s * 136 + c] = f2bf((x[j] - mu) * rstd * lmg[c] + lmb[c]);
    }
  }
  __syncthreads();
  // MLP1: hid = relu(LN(h) @ W1 + b1)   (wave: cols wave*128..+128)
  {
    bf16x8 xa[4];
#pragma unroll
    for (int ks = 0; ks < 4; ++ks)
      xa[ks] = *(const bf16x8*)&xbf[lm * 136 + ks * 32 + lq * 8];
    const f32x4 z4 = {0.f, 0.f, 0.f, 0.f};
    f32x4 m1[8];
#pragma unroll
    for (int t = 0; t < 8; ++t) m1[t] = z4;
#pragma unroll
    for (int ks = 0; ks < 4; ++ks)
#pragma unroll
      for (int t = 0; t < 8; ++t) {
        const int col = wave * 128 + t * 16 + lm;
        m1[t] = mfma16(xa[ks], *(const bf16x8*)&W1t[(long long)col * 128 + ks * 32 + lq * 8], m1[t]);
      }
#pragma unroll
    for (int t = 0; t < 8; ++t)
#pragma unroll
      for (int r = 0; r < 4; ++r) {
        const int col = wave * 128 + t * 16 + lm, s = lq * 4 + r;
        hidbf[s * 520 + col] = f2bf(fmaxf(m1[t][r] + b1[col], 0.f));
      }
  }
  __syncthreads();
  // MLP2 + residual: out = h + hid @ W2 + b2  (wave: cols wave*32..+32)
  {
    const f32x4 z4 = {0.f, 0.f, 0.f, 0.f};
    f32x4 m2a = z4, m2b = z4;
#pragma unroll
    for (int ks = 0; ks < 16; ++ks) {
      const bf16x8 xa = *(const bf16x8*)&hidbf[lm * 520 + ks * 32 + lq * 8];
      m2a = mfma16(xa, *(const bf16x8*)&W2t[(long long)(wave * 32 + lm) * 512 + ks * 32 + lq * 8], m2a);
      m2b = mfma16(xa, *(const bf16x8*)&W2t[(long long)(wave * 32 + 16 + lm) * 512 + ks * 32 + lq * 8], m2b);
    }
#pragma unroll
    for (int r = 0; r < 4; ++r) {
      const int s = lq * 4 + r;
      const int c0 = wave * 32 + lm, c1 = c0 + 16;
      const float o0 = m2a[r] + b2[c0] + hsp[s * 128 + c0];
      const float o1 = m2b[r] + b2[c1] + hsp[s * 128 + c1];
      float* o = slots_out + ((long long)b * 16 + s) * 128;
      o[c0] = o0; o[c1] = o1;
      if (last) {
        float* d = dout + ((long long)b * 16 + s) * 128;
        d[c0] = o0; d[c1] = o1;
      }
    }
  }
}

extern "C" void kernel_launch(void* const* d_in, const int* in_sizes, int n_in,
                              void* d_out, int out_size, void* d_ws, size_t ws_size,
                              hipStream_t stream) {
  (void)in_sizes; (void)n_in; (void)out_size; (void)ws_size;
  const float* feats    = (const float*)d_in[0];
  const float* slots0   = (const float*)d_in[1];
  const int*   is_first = (const int*)d_in[2];
  const float* ln_in_g  = (const float*)d_in[3];
  const float* ln_in_b  = (const float*)d_in[4];
  const float* ln_sl_g  = (const float*)d_in[5];
  const float* ln_sl_b  = (const float*)d_in[6];
  const float* ln_ml_g  = (const float*)d_in[7];
  const float* ln_ml_b  = (const float*)d_in[8];
  const float* Wq  = (const float*)d_in[9];
  const float* bq  = (const float*)d_in[10];
  const float* Wk  = (const float*)d_in[11];
  const float* bk  = (const float*)d_in[12];
  const float* Wv  = (const float*)d_in[13];
  const float* bv  = (const float*)d_in[14];
  const float* Wih_f = (const float*)d_in[15];
  const float* Whh_f = (const float*)d_in[16];
  const float* bih = (const float*)d_in[17];
  const float* bhh = (const float*)d_in[18];
  const float* W1  = (const float*)d_in[19];
  const float* b1  = (const float*)d_in[20];
  const float* W2  = (const float*)d_in[21];
  const float* b2  = (const float*)d_in[22];

  char* ws = (char*)d_ws;
  size_t off = 0;
  auto alloc = [&](size_t bytes) -> void* {
    void* p = ws + off;
    off = (off + bytes + 255) & ~(size_t)255;
    return p;
  };
  u16* kbuf   = (u16*)alloc((size_t)64 * 4096 * 128 * 2);
  u16* vt     = (u16*)alloc((size_t)64 * 4096 * 128 * 2);
  u16* Wcat   = (u16*)alloc((size_t)16 * 256 * 32 * 2);
  u16* Wqt    = (u16*)alloc((size_t)128 * 128 * 2);
  u16* Wih    = (u16*)alloc((size_t)384 * 128 * 2);
  u16* Whh    = (u16*)alloc((size_t)384 * 128 * 2);
  u16* W1t    = (u16*)alloc((size_t)512 * 128 * 2);
  u16* W2t    = (u16*)alloc((size_t)128 * 512 * 2);
  float* updp = (float*)alloc((size_t)64 * 8 * 2048 * 4);
  float* rsp  = (float*)alloc((size_t)64 * 8 * 16 * 4);
  float* slA  = (float*)alloc((size_t)64 * 2048 * 4);
  float* slB  = (float*)alloc((size_t)64 * 2048 * 4);

  // weight conversions (bf16, layouts for MFMA B-fragments)
  cvt_ktile<<<256, 256, 0, stream>>>(Wk, Wcat, 0);
  cvt_ktile<<<256, 256, 0, stream>>>(Wv, Wcat, 128);
  cvt_kernel<<<64, 256, 0, stream>>>(Wq, Wqt, 128, 128, 1);
  cvt_kernel<<<64, 256, 0, stream>>>(Wih_f, Wih, 384, 128, 0);
  cvt_kernel<<<64, 256, 0, stream>>>(Whh_f, Whh, 384, 128, 0);
  cvt_kernel<<<64, 256, 0, stream>>>(W1, W1t, 128, 512, 1);
  cvt_kernel<<<64, 256, 0, stream>>>(W2, W2t, 512, 128, 1);

  k1_lnproj<<<16384, 256, 0, stream>>>(feats, ln_in_g, ln_in_b, Wcat, bk, bv, kbuf, vt);

  float* bufs[2] = {slA, slB};
  for (int it = 0; it < 3; ++it) {
    const float* sin_ = (it == 0) ? slots0 : bufs[(it + 1) & 1];
    float* sout = bufs[it & 1];
    k3_attn<<<512, 256, 0, stream>>>(sin_, is_first, it, ln_sl_g, ln_sl_b, Wqt, bq,
                                     kbuf, vt, updp, rsp);
    k4_update<<<64, 256, 0, stream>>>(sin_, is_first, it, updp, rsp, Wih, Whh,
                                      bih, bhh, ln_ml_g, ln_ml_b, W1t, b1, W2t, b2,
                                      sout, (float*)d_out);
  }
}

// Round 11
// 512.515 us; speedup vs baseline: 1.0476x; 1.0476x over previous
//
#include <hip/hip_runtime.h>

typedef __attribute__((ext_vector_type(4))) float f32x4;
typedef __attribute__((ext_vector_type(8))) short bf16x8;
typedef unsigned short u16;

#define LNEPS 1e-3f
#define ATTN_EPS 1e-8f
#define SCALE 0.044194173824159216f  // 512^-0.5

__device__ __forceinline__ u16 f2bf(float f) {
  union { float f; unsigned u; } v; v.f = f;
  unsigned r = v.u + 0x7fffu + ((v.u >> 16) & 1u);
  return (u16)(r >> 16);
}
__device__ __forceinline__ float bf2f(unsigned u) {
  union { float f; unsigned u; } v; v.u = (u & 0xffffu) << 16; return v.f;
}
__device__ __forceinline__ f32x4 mfma16(bf16x8 a, bf16x8 b, f32x4 c) {
  return __builtin_amdgcn_mfma_f32_16x16x32_bf16(a, b, c, 0, 0, 0);
}
__device__ __forceinline__ unsigned pk2(float a, float b) {
  return (unsigned)f2bf(a) | ((unsigned)f2bf(b) << 16);
}
// async global->LDS DMA, 16B per lane: global src is PER-LANE, LDS dst is
// wave-uniform base (+lane*16 applied by HW). m97/m104 semantics.
__device__ __forceinline__ void gload_lds16(const void* g, void* l) {
  __builtin_amdgcn_global_load_lds(
      (const __attribute__((address_space(1))) void*)g,
      (__attribute__((address_space(3))) void*)l, 16, 0, 0);
}

// ---------------- weight convert / transpose to bf16 ----------------
__global__ void cvt_kernel(const float* __restrict__ src, u16* __restrict__ dst,
                           int rows, int cols, int trans) {
  const int total = rows * cols;
  for (int i = blockIdx.x * blockDim.x + threadIdx.x; i < total;
       i += gridDim.x * blockDim.x) {
    const int r = i / cols, c = i - r * cols;
    const u16 v = f2bf(src[i]);
    dst[trans ? (c * rows + r) : i] = v;
  }
}

// k-slab layout for GEMM B: dst[ks][c+coff][q] = src[(ks*32+q)*128 + c]
__global__ void cvt_ktile(const float* __restrict__ src, u16* __restrict__ dst,
                          int coff) {
  const int i = blockIdx.x * blockDim.x + threadIdx.x;  // over 512*128
  if (i < 512 * 128) {
    const int k = i >> 7, c = i & 127;
    dst[(k >> 5) * 8192 + (c + coff) * 32 + (k & 31)] = f2bf(src[i]);
  }
}

// ---------------- K1: LN(features) -> k,v projections ----------------
// grid 16384 blocks x 256 thr (4 waves). Block: 16 rows x 256 cols, K=512.
// Phase 1 via global_load_lds DMA (no VGPR staging, loads can't be "sunk"):
//   raw fp32 tile 16x512 -> LDS linearly (32 x 1KB instrs), barrier,
//   stats from LDS column-strided (conflict-free) + PROVEN butterfly,
//   LN in-place: bf16 A-tile (proven XOR-swizzle layout) overwrites the
//   raw row's first 1KB (safe: wave lockstep, per-row wave ownership).
// 32KB LDS -> 5 blocks/CU (20 waves). GEMM/epilogue = r10 (A stride 2048).
__global__ __launch_bounds__(256, 5) void k1_lnproj(
    const float* __restrict__ feats, const float* __restrict__ lng,
    const float* __restrict__ lnb, const u16* __restrict__ Wcat,
    const float* __restrict__ bk, const float* __restrict__ bv,
    u16* __restrict__ kbuf, u16* __restrict__ vt) {
  __shared__ alignas(16) union {
    float raw[16 * 512];                                // 32768 B
    struct { u16 kq[16 * 136]; float c[128 * 20]; } e;  // 4352+10240 B
  } sm;
  const int tid = threadIdx.x;
  const int wave = tid >> 6, lane = tid & 63;
  const int lq = lane >> 4, lm = lane & 15;
  const long long row0 = (long long)blockIdx.x * 16;

  // ---- phase 0: issue all DMA (8 x 1KB per wave), zero VGPR staging ----
  {
    const char* gsrc = (const char*)(feats + row0 * 512);
#pragma unroll
    for (int jj = 0; jj < 8; ++jj) {
      const int inst = wave * 8 + jj;
      gload_lds16(gsrc + inst * 1024 + lane * 16,
                  (char*)sm.raw + inst * 1024);
    }
  }
  // LN params for this lane's strided elements (independent of DMA)
  float gj[8], bj[8];
#pragma unroll
  for (int j = 0; j < 8; ++j) {
    gj[j] = lng[lane + 64 * j];
    bj[j] = lnb[lane + 64 * j];
  }
  __syncthreads();  // drains vmcnt: DMA complete

  // ---- phase 1: per-row stats (butterfly) + LN, in place ----
  {
#pragma unroll
    for (int i = 0; i < 4; ++i) {
      const int row = wave * 4 + i;
      float x[8];
#pragma unroll
      for (int j = 0; j < 8; ++j)
        x[j] = sm.raw[row * 512 + lane + 64 * j];  // bank=lane%32: free
      float s = ((x[0] + x[1]) + (x[2] + x[3])) +
                ((x[4] + x[5]) + (x[6] + x[7]));
      float q = x[0] * x[0] + x[1] * x[1] + x[2] * x[2] + x[3] * x[3] +
                x[4] * x[4] + x[5] * x[5] + x[6] * x[6] + x[7] * x[7];
#pragma unroll
      for (int m = 1; m < 64; m <<= 1) {
        s += __shfl_xor(s, m);
        q += __shfl_xor(q, m);
      }
      const float mu = s * (1.f / 512.f);
      const float rstd = rsqrtf(q * (1.f / 512.f) - mu * mu + LNEPS);
      char* arow = (char*)sm.raw + row * 2048;
      const int swz = (row & 7) << 4;
#pragma unroll
      for (int j = 0; j < 8; ++j) {
        const u16 yb = f2bf((x[j] - mu) * rstd * gj[j] + bj[j]);
        *(u16*)(arow + ((2 * (lane + 64 * j)) ^ swz)) = yb;
      }
    }
  }
  __syncthreads();

  // ---- GEMM: wave = col-quarter cq; rows 0..15 (1 m-tile) ----
  const int cq = wave;
  f32x4 acc[4];
  {
    const f32x4 z4 = {0.f, 0.f, 0.f, 0.f};
#pragma unroll
    for (int n = 0; n < 4; ++n) acc[n] = z4;
  }
  const u16* wb = Wcat + (cq * 64 + lm) * 32 + lq * 8;  // k-slab base
#pragma unroll 4
  for (int ks = 0; ks < 16; ++ks) {
    const int row = lm;
    const bf16x8 a = *(const bf16x8*)((const char*)sm.raw + row * 2048 +
                                      ((ks * 64 + lq * 16) ^ ((row & 7) << 4)));
    bf16x8 b[4];
#pragma unroll
    for (int nt = 0; nt < 4; ++nt)
      b[nt] = *(const bf16x8*)&wb[ks * 8192 + nt * 512];
#pragma unroll
    for (int nt = 0; nt < 4; ++nt)
      acc[nt] = mfma16(a, b[nt], acc[nt]);
  }
  __syncthreads();  // A-tile dead; union becomes epilogue staging

  // ---- epilogue staging: k (bf16) and v (fp32, transposed) into LDS ----
  if (cq < 2) {
#pragma unroll
    for (int nt = 0; nt < 4; ++nt) {
      const int col = cq * 64 + nt * 16 + lm;
      const float bias = bk[col];
#pragma unroll
      for (int r = 0; r < 4; ++r) {
        const int row = lq * 4 + r;
        sm.e.kq[row * 136 + col] = f2bf(acc[nt][r] + bias);
      }
    }
  } else {
#pragma unroll
    for (int nt = 0; nt < 4; ++nt) {
      const int d = (cq - 2) * 64 + nt * 16 + lm;
      const float bias = bv[d];
#pragma unroll
      for (int r = 0; r < 4; ++r) {
        const int row = lq * 4 + r;
        sm.e.c[d * 20 + row] = acc[nt][r] + bias;
      }
    }
  }
  __syncthreads();

  const long long bidx = row0 >> 12;
  const int nbase = (int)(row0 & 4095);
  // ---- pack k: 16 rows x 128 cols, coalesced 16B stores (all 256 thr) ----
  {
    const int row = tid >> 4, c0 = (tid & 15) * 8;
    const u16* sp = &sm.e.kq[row * 136 + c0];
    u16* dst = kbuf + (row0 + row) * 128 + c0;
    *(uint4*)(dst) = *(const uint4*)(sp);
  }
  // ---- pack v^T: [d][N] bf16 (all 256 thr) ----
  {
    const int d = tid >> 1, nh = (tid & 1) * 8;
    const float* cp = &sm.e.c[d * 20 + nh];
    u16* dst = vt + (bidx * 128 + d) * 4096 + nbase + nh;
    uint4 p;
    p.x = pk2(cp[0], cp[1]);
    p.y = pk2(cp[2], cp[3]);
    p.z = pk2(cp[4], cp[5]);
    p.w = pk2(cp[6], cp[7]);
    *(uint4*)(dst) = p;
  }
}

// ---------------- K3: q-proj + dots + slot-softmax + P@v partials ----------
// grid 512 blocks (64 batches x 8 chunks), 256 thr. Wave handles 128 tokens.
__global__ __launch_bounds__(256) void k3_attn(
    const float* __restrict__ slots_in, const int* __restrict__ is_first, int iter,
    const float* __restrict__ lsg, const float* __restrict__ lsb,
    const u16* __restrict__ Wqt, const float* __restrict__ bq,
    const u16* __restrict__ kbuf, const u16* __restrict__ vt,
    float* __restrict__ updp, float* __restrict__ rsp) {
  const int ni = (*is_first) ? 3 : 2;
  if (iter >= ni) return;
  __shared__ alignas(16) u16 slns[16 * 136];
  __shared__ alignas(16) u16 qlds[16 * 136];
  __shared__ alignas(16) u16 plds[4][640];
  __shared__ alignas(16) float ures[4][16 * 128];
  __shared__ float rres[4][16];
  const int tid = threadIdx.x;
  const int wave = tid >> 6, lane = tid & 63;
  const int lq = lane >> 4, lm = lane & 15;
  const int b = blockIdx.x >> 3, chunk = blockIdx.x & 7;

  // LN(slots) by wave 0
  if (wave == 0) {
    const int s = lane >> 2, cc = (lane & 3) * 32;
    const float* sp = slots_in + ((long long)b * 16 + s) * 128 + cc;
    float x[32];
    float sum = 0.f, sq = 0.f;
#pragma unroll
    for (int j = 0; j < 32; ++j) { x[j] = sp[j]; sum += x[j]; sq += x[j] * x[j]; }
    sum += __shfl_xor(sum, 1); sum += __shfl_xor(sum, 2);
    sq  += __shfl_xor(sq, 1);  sq  += __shfl_xor(sq, 2);
    const float mu = sum * (1.f / 128.f);
    const float rstd = rsqrtf(sq * (1.f / 128.f) - mu * mu + LNEPS);
#pragma unroll
    for (int j = 0; j < 32; ++j) {
      const int c = cc + j;
      slns[s * 136 + c] = f2bf((x[j] - mu) * rstd * lsg[c] + lsb[c]);
    }
  }
  __syncthreads();
  // q = LN(slots) @ Wq + bq ; wave computes cols [wave*32, wave*32+32)
  {
    f32x4 qa0 = {0.f, 0.f, 0.f, 0.f}, qa1 = {0.f, 0.f, 0.f, 0.f};
#pragma unroll
    for (int ks = 0; ks < 4; ++ks) {
      const bf16x8 af = *(const bf16x8*)&slns[lm * 136 + ks * 32 + lq * 8];
      const bf16x8 b0 = *(const bf16x8*)&Wqt[(wave * 32 + lm) * 128 + ks * 32 + lq * 8];
      const bf16x8 b1 = *(const bf16x8*)&Wqt[(wave * 32 + 16 + lm) * 128 + ks * 32 + lq * 8];
      qa0 = mfma16(af, b0, qa0);
      qa1 = mfma16(af, b1, qa1);
    }
#pragma unroll
    for (int r = 0; r < 4; ++r) {
      const int s = lq * 4 + r;
      const int c0 = wave * 32 + lm, c1 = c0 + 16;
      qlds[s * 136 + c0] = f2bf(qa0[r] + bq[c0]);
      qlds[s * 136 + c1] = f2bf(qa1[r] + bq[c1]);
    }
  }
  __syncthreads();

  bf16x8 qf[4];
#pragma unroll
  for (int ks = 0; ks < 4; ++ks)
    qf[ks] = *(const bf16x8*)&qlds[lm * 136 + ks * 32 + lq * 8];

  float rs0 = 0.f, rs1 = 0.f, rs2 = 0.f, rs3 = 0.f;
  const f32x4 z4 = {0.f, 0.f, 0.f, 0.f};
  f32x4 uacc[8];
#pragma unroll
  for (int i = 0; i < 8; ++i) uacc[i] = z4;
  u16* pw = plds[wave];
  const int n0w = chunk * 512 + wave * 128;
  const u16* kb = kbuf + (long long)b * 4096 * 128;
  const u16* vb = vt + (long long)b * 128 * 4096;

  for (int g = 0; g < 4; ++g) {
    const int nb = n0w + g * 32;
#pragma unroll
    for (int sub = 0; sub < 2; ++sub) {
      f32x4 dot = z4;
      const u16* kr = kb + (long long)(nb + sub * 16 + lm) * 128 + lq * 8;
#pragma unroll
      for (int ks = 0; ks < 4; ++ks)
        dot = mfma16(qf[ks], *(const bf16x8*)&kr[ks * 32], dot);
      const float d0 = dot[0] * SCALE, d1 = dot[1] * SCALE;
      const float d2 = dot[2] * SCALE, d3 = dot[3] * SCALE;
      float m = fmaxf(fmaxf(d0, d1), fmaxf(d2, d3));
      m = fmaxf(m, __shfl_xor(m, 16));
      m = fmaxf(m, __shfl_xor(m, 32));
      const float e0 = __expf(d0 - m), e1 = __expf(d1 - m);
      const float e2 = __expf(d2 - m), e3 = __expf(d3 - m);
      float ss = e0 + e1 + e2 + e3;
      ss += __shfl_xor(ss, 16);
      ss += __shfl_xor(ss, 32);
      const float inv = 1.f / ss;
      const float p0 = e0 * inv + ATTN_EPS, p1 = e1 * inv + ATTN_EPS;
      const float p2 = e2 * inv + ATTN_EPS, p3 = e3 * inv + ATTN_EPS;
      rs0 += p0; rs1 += p1; rs2 += p2; rs3 += p3;
      const int nc = sub * 16 + lm;
      pw[(lq * 4 + 0) * 40 + nc] = f2bf(p0);
      pw[(lq * 4 + 1) * 40 + nc] = f2bf(p1);
      pw[(lq * 4 + 2) * 40 + nc] = f2bf(p2);
      pw[(lq * 4 + 3) * 40 + nc] = f2bf(p3);
    }
    const bf16x8 pa = *(const bf16x8*)&pw[lm * 40 + lq * 8];
    const u16* vr = vb + (long long)lm * 4096 + nb + lq * 8;
#pragma unroll
    for (int dt = 0; dt < 8; ++dt)
      uacc[dt] = mfma16(pa, *(const bf16x8*)&vr[(long long)dt * 16 * 4096], uacc[dt]);
  }
  // rowsum reduce across the 16 lanes of each quarter
#pragma unroll
  for (int msk = 1; msk < 16; msk <<= 1) {
    rs0 += __shfl_xor(rs0, msk); rs1 += __shfl_xor(rs1, msk);
    rs2 += __shfl_xor(rs2, msk); rs3 += __shfl_xor(rs3, msk);
  }
#pragma unroll
  for (int dt = 0; dt < 8; ++dt)
#pragma unroll
    for (int r = 0; r < 4; ++r)
      ures[wave][(lq * 4 + r) * 128 + dt * 16 + lm] = uacc[dt][r];
  if (lm == 0) {
    rres[wave][lq * 4 + 0] = rs0; rres[wave][lq * 4 + 1] = rs1;
    rres[wave][lq * 4 + 2] = rs2; rres[wave][lq * 4 + 3] = rs3;
  }
  __syncthreads();
  {
    const int e0 = tid * 8;
    float* dst = updp + (long long)(b * 8 + chunk) * 2048 + e0;
#pragma unroll
    for (int e = 0; e < 8; ++e)
      dst[e] = ures[0][e0 + e] + ures[1][e0 + e] + ures[2][e0 + e] + ures[3][e0 + e];
  }
  if (tid < 16)
    rsp[(b * 8 + chunk) * 16 + tid] =
        rres[0][tid] + rres[1][tid] + rres[2][tid] + rres[3][tid];
}

// ---------------- K4: reduce partials + GRU + MLP -> new slots -------------
// grid 64 blocks (batch), 256 thr.
__global__ __launch_bounds__(256) void k4_update(
    const float* __restrict__ slots_in, const int* __restrict__ is_first, int iter,
    const float* __restrict__ updp, const float* __restrict__ rsp,
    const u16* __restrict__ Wih, const u16* __restrict__ Whh,
    const float* __restrict__ bih, const float* __restrict__ bhh,
    const float* __restrict__ lmg, const float* __restrict__ lmb,
    const u16* __restrict__ W1t, const float* __restrict__ b1,
    const u16* __restrict__ W2t, const float* __restrict__ b2,
    float* __restrict__ slots_out, float* __restrict__ dout) {
  const int ni = (*is_first) ? 3 : 2;
  if (iter >= ni) return;
  const bool last = (iter == ni - 1);
  __shared__ float g_ih[16 * 392];
  __shared__ float g_hh[16 * 392];
  __shared__ alignas(16) float hsp[16 * 128];
  __shared__ float rsum[16];
  __shared__ alignas(16) u16 ubf[16 * 136];
  __shared__ alignas(16) u16 xbf[16 * 136];
  __shared__ alignas(16) u16 hidbf[16 * 520];
  const int tid = threadIdx.x;
  const int wave = tid >> 6, lane = tid & 63;
  const int lq = lane >> 4, lm = lane & 15;
  const int b = blockIdx.x;
  const int es = tid >> 4;         // slot row for this thread's 8 elems
  const int ej = (tid & 15) * 8;   // col start

  // slots_prev -> hsp (fp32) and xbf (bf16)
  {
    const float* sp = slots_in + (long long)b * 2048 + tid * 8;
    const float4 a = ((const float4*)sp)[0], c = ((const float4*)sp)[1];
    *(float4*)&hsp[tid * 8] = a;
    *(float4*)&hsp[tid * 8 + 4] = c;
    uint4 p;
    p.x = pk2(a.x, a.y);
    p.y = pk2(a.z, a.w);
    p.z = pk2(c.x, c.y);
    p.w = pk2(c.z, c.w);
    *(uint4*)&xbf[es * 136 + ej] = p;
  }
  if (tid < 16) {
    float s = 0.f;
    for (int p = 0; p < 8; ++p) s += rsp[(b * 8 + p) * 16 + tid];
    rsum[tid] = s;
  }
  __syncthreads();
  // reduce updates partials, normalize by rowsum -> ubf (bf16)
  {
    float acc[8];
#pragma unroll
    for (int e = 0; e < 8; ++e) acc[e] = 0.f;
    for (int p = 0; p < 8; ++p) {
      const float* src = updp + (long long)(b * 8 + p) * 2048 + tid * 8;
      const float4 x = ((const float4*)src)[0], y = ((const float4*)src)[1];
      acc[0] += x.x; acc[1] += x.y; acc[2] += x.z; acc[3] += x.w;
      acc[4] += y.x; acc[5] += y.y; acc[6] += y.z; acc[7] += y.w;
    }
    const float inv = 1.f / rsum[es];
    uint4 p;
    p.x = pk2(acc[0] * inv, acc[1] * inv);
    p.y = pk2(acc[2] * inv, acc[3] * inv);
    p.z = pk2(acc[4] * inv, acc[5] * inv);
    p.w = pk2(acc[6] * inv, acc[7] * inv);
    *(uint4*)&ubf[es * 136 + ej] = p;
  }
  __syncthreads();
  // gi = u @ Wih^T + bih ; gh = h @ Whh^T + bhh  (wave: cols wave*96..+96)
  {
    bf16x8 ua[4], ha[4];
#pragma unroll
    for (int ks = 0; ks < 4; ++ks) {
      ua[ks] = *(const bf16x8*)&ubf[lm * 136 + ks * 32 + lq * 8];
      ha[ks] = *(const bf16x8*)&xbf[lm * 136 + ks * 32 + lq * 8];
    }
    const f32x4 z4 = {0.f, 0.f, 0.f, 0.f};
    f32x4 gi[6], gh[6];
#pragma unroll
    for (int t = 0; t < 6; ++t) { gi[t] = z4; gh[t] = z4; }
#pragma unroll
    for (int ks = 0; ks < 4; ++ks)
#pragma unroll
      for (int t = 0; t < 6; ++t) {
        const int col = wave * 96 + t * 16 + lm;
        gi[t] = mfma16(ua[ks], *(const bf16x8*)&Wih[(long long)col * 128 + ks * 32 + lq * 8], gi[t]);
        gh[t] = mfma16(ha[ks], *(const bf16x8*)&Whh[(long long)col * 128 + ks * 32 + lq * 8], gh[t]);
      }
#pragma unroll
    for (int t = 0; t < 6; ++t)
#pragma unroll
      for (int r = 0; r < 4; ++r) {
        const int col = wave * 96 + t * 16 + lm, s = lq * 4 + r;
        g_ih[s * 392 + col] = gi[t][r] + bih[col];
        g_hh[s * 392 + col] = gh[t][r] + bhh[col];
      }
  }
  __syncthreads();
  // gates (elementwise), h overwrites hsp
  {
#pragma unroll
    for (int e = 0; e < 8; ++e) {
      const int j = ej + e;
      const float sr = g_ih[es * 392 + j] + g_hh[es * 392 + j];
      const float sz = g_ih[es * 392 + 128 + j] + g_hh[es * 392 + 128 + j];
      const float r = 1.f / (1.f + __expf(-sr));
      const float z = 1.f / (1.f + __expf(-sz));
      const float n = tanhf(g_ih[es * 392 + 256 + j] + r * g_hh[es * 392 + 256 + j]);
      hsp[es * 128 + j] = (1.f - z) * n + z * hsp[es * 128 + j];
    }
  }
  __syncthreads();
  // LN(h) -> xbf (wave 0)
  if (wave == 0) {
    const int s = lane >> 2, cc = (lane & 3) * 32;
    float x[32];
    float sum = 0.f, sq = 0.f;
#pragma unroll
    for (int j = 0; j < 32; ++j) {
      x[j] = hsp[s * 128 + cc + j]; sum += x[j]; sq += x[j] * x[j];
    }
    sum += __shfl_xor(sum, 1); sum += __shfl_xor(sum, 2);
    sq  += __shfl_xor(sq, 1);  sq  += __shfl_xor(sq, 2);
    const float mu = sum * (1.f / 128.f);
    const float rstd = rsqrtf(sq * (1.f / 128.f) - mu * mu + LNEPS);
#pragma unroll
    for (int j = 0; j < 32; ++j) {
      const int c = cc + j;
      xbf[s * 136 + c] = f2bf((x[j] - mu) * rstd * lmg[c] + lmb[c]);
    }
  }
  __syncthreads();
  // MLP1: hid = relu(LN(h) @ W1 + b1)   (wave: cols wave*128..+128)
  {
    bf16x8 xa[4];
#pragma unroll
    for (int ks = 0; ks < 4; ++ks)
      xa[ks] = *(const bf16x8*)&xbf[lm * 136 + ks * 32 + lq * 8];
    const f32x4 z4 = {0.f, 0.f, 0.f, 0.f};
    f32x4 m1[8];
#pragma unroll
    for (int t = 0; t < 8; ++t) m1[t] = z4;
#pragma unroll
    for (int ks = 0; ks < 4; ++ks)
#pragma unroll
      for (int t = 0; t < 8; ++t) {
        const int col = wave * 128 + t * 16 + lm;
        m1[t] = mfma16(xa[ks], *(const bf16x8*)&W1t[(long long)col * 128 + ks * 32 + lq * 8], m1[t]);
      }
#pragma unroll
    for (int t = 0; t < 8; ++t)
#pragma unroll
      for (int r = 0; r < 4; ++r) {
        const int col = wave * 128 + t * 16 + lm, s = lq * 4 + r;
        hidbf[s * 520 + col] = f2bf(fmaxf(m1[t][r] + b1[col], 0.f));
      }
  }
  __syncthreads();
  // MLP2 + residual: out = h + hid @ W2 + b2  (wave: cols wave*32..+32)
  {
    const f32x4 z4 = {0.f, 0.f, 0.f, 0.f};
    f32x4 m2a = z4, m2b = z4;
#pragma unroll
    for (int ks = 0; ks < 16; ++ks) {
      const bf16x8 xa = *(const bf16x8*)&hidbf[lm * 520 + ks * 32 + lq * 8];
      m2a = mfma16(xa, *(const bf16x8*)&W2t[(long long)(wave * 32 + lm) * 512 + ks * 32 + lq * 8], m2a);
      m2b = mfma16(xa, *(const bf16x8*)&W2t[(long long)(wave * 32 + 16 + lm) * 512 + ks * 32 + lq * 8], m2b);
    }
#pragma unroll
    for (int r = 0; r < 4; ++r) {
      const int s = lq * 4 + r;
      const int c0 = wave * 32 + lm, c1 = c0 + 16;
      const float o0 = m2a[r] + b2[c0] + hsp[s * 128 + c0];
      const float o1 = m2b[r] + b2[c1] + hsp[s * 128 + c1];
      float* o = slots_out + ((long long)b * 16 + s) * 128;
      o[c0] = o0; o[c1] = o1;
      if (last) {
        float* d = dout + ((long long)b * 16 + s) * 128;
        d[c0] = o0; d[c1] = o1;
      }
    }
  }
}

extern "C" void kernel_launch(void* const* d_in, const int* in_sizes, int n_in,
                              void* d_out, int out_size, void* d_ws, size_t ws_size,
                              hipStream_t stream) {
  (void)in_sizes; (void)n_in; (void)out_size; (void)ws_size;
  const float* feats    = (const float*)d_in[0];
  const float* slots0   = (const float*)d_in[1];
  const int*   is_first = (const int*)d_in[2];
  const float* ln_in_g  = (const float*)d_in[3];
  const float* ln_in_b  = (const float*)d_in[4];
  const float* ln_sl_g  = (const float*)d_in[5];
  const float* ln_sl_b  = (const float*)d_in[6];
  const float* ln_ml_g  = (const float*)d_in[7];
  const float* ln_ml_b  = (const float*)d_in[8];
  const float* Wq  = (const float*)d_in[9];
  const float* bq  = (const float*)d_in[10];
  const float* Wk  = (const float*)d_in[11];
  const float* bk  = (const float*)d_in[12];
  const float* Wv  = (const float*)d_in[13];
  const float* bv  = (const float*)d_in[14];
  const float* Wih_f = (const float*)d_in[15];
  const float* Whh_f = (const float*)d_in[16];
  const float* bih = (const float*)d_in[17];
  const float* bhh = (const float*)d_in[18];
  const float* W1  = (const float*)d_in[19];
  const float* b1  = (const float*)d_in[20];
  const float* W2  = (const float*)d_in[21];
  const float* b2  = (const float*)d_in[22];

  char* ws = (char*)d_ws;
  size_t off = 0;
  auto alloc = [&](size_t bytes) -> void* {
    void* p = ws + off;
    off = (off + bytes + 255) & ~(size_t)255;
    return p;
  };
  u16* kbuf   = (u16*)alloc((size_t)64 * 4096 * 128 * 2);
  u16* vt     = (u16*)alloc((size_t)64 * 4096 * 128 * 2);
  u16* Wcat   = (u16*)alloc((size_t)16 * 256 * 32 * 2);
  u16* Wqt    = (u16*)alloc((size_t)128 * 128 * 2);
  u16* Wih    = (u16*)alloc((size_t)384 * 128 * 2);
  u16* Whh    = (u16*)alloc((size_t)384 * 128 * 2);
  u16* W1t    = (u16*)alloc((size_t)512 * 128 * 2);
  u16* W2t    = (u16*)alloc((size_t)128 * 512 * 2);
  float* updp = (float*)alloc((size_t)64 * 8 * 2048 * 4);
  float* rsp  = (float*)alloc((size_t)64 * 8 * 16 * 4);
  float* slA  = (float*)alloc((size_t)64 * 2048 * 4);
  float* slB  = (float*)alloc((size_t)64 * 2048 * 4);

  // weight conversions (bf16, layouts for MFMA B-fragments)
  cvt_ktile<<<256, 256, 0, stream>>>(Wk, Wcat, 0);
  cvt_ktile<<<256, 256, 0, stream>>>(Wv, Wcat, 128);
  cvt_kernel<<<64, 256, 0, stream>>>(Wq, Wqt, 128, 128, 1);
  cvt_kernel<<<64, 256, 0, stream>>>(Wih_f, Wih, 384, 128, 0);
  cvt_kernel<<<64, 256, 0, stream>>>(Whh_f, Whh, 384, 128, 0);
  cvt_kernel<<<64, 256, 0, stream>>>(W1, W1t, 128, 512, 1);
  cvt_kernel<<<64, 256, 0, stream>>>(W2, W2t, 512, 128, 1);

  k1_lnproj<<<16384, 256, 0, stream>>>(feats, ln_in_g, ln_in_b, Wcat, bk, bv, kbuf, vt);

  float* bufs[2] = {slA, slB};
  for (int it = 0; it < 3; ++it) {
    const float* sin_ = (it == 0) ? slots0 : bufs[(it + 1) & 1];
    float* sout = bufs[it & 1];
    k3_attn<<<512, 256, 0, stream>>>(sin_, is_first, it, ln_sl_g, ln_sl_b, Wqt, bq,
                                     kbuf, vt, updp, rsp);
    k4_update<<<64, 256, 0, stream>>>(sin_, is_first, it, updp, rsp, Wih, Whh,
                                      bih, bhh, ln_ml_g, ln_ml_b, W1t, b1, W2t, b2,
                                      sout, (float*)d_out);
  }
}

// Round 12
// 511.913 us; speedup vs baseline: 1.0489x; 1.0012x over previous
//
#include <hip/hip_runtime.h>

typedef __attribute__((ext_vector_type(4))) float f32x4;
typedef __attribute__((ext_vector_type(8))) short bf16x8;
typedef unsigned short u16;

#define LNEPS 1e-3f
#define ATTN_EPS 1e-8f
#define SCALE 0.044194173824159216f  // 512^-0.5

__device__ __forceinline__ u16 f2bf(float f) {
  union { float f; unsigned u; } v; v.f = f;
  unsigned r = v.u + 0x7fffu + ((v.u >> 16) & 1u);
  return (u16)(r >> 16);
}
__device__ __forceinline__ float bf2f(unsigned u) {
  union { float f; unsigned u; } v; v.u = (u & 0xffffu) << 16; return v.f;
}
__device__ __forceinline__ f32x4 mfma16(bf16x8 a, bf16x8 b, f32x4 c) {
  return __builtin_amdgcn_mfma_f32_16x16x32_bf16(a, b, c, 0, 0, 0);
}
__device__ __forceinline__ unsigned pk2(float a, float b) {
  return (unsigned)f2bf(a) | ((unsigned)f2bf(b) << 16);
}
// async global->LDS DMA, 16B/lane: global src PER-LANE, LDS dst wave-uniform
__device__ __forceinline__ void gload_lds16(const void* g, void* l) {
  __builtin_amdgcn_global_load_lds(
      (const __attribute__((address_space(1))) void*)g,
      (__attribute__((address_space(3))) void*)l, 16, 0, 0);
}

// ---------------- weight convert / transpose to bf16 ----------------
__global__ void cvt_kernel(const float* __restrict__ src, u16* __restrict__ dst,
                           int rows, int cols, int trans) {
  const int total = rows * cols;
  for (int i = blockIdx.x * blockDim.x + threadIdx.x; i < total;
       i += gridDim.x * blockDim.x) {
    const int r = i / cols, c = i - r * cols;
    const u16 v = f2bf(src[i]);
    dst[trans ? (c * rows + r) : i] = v;
  }
}

// k-slab layout for GEMM B: dst[ks][c+coff][q] = src[(ks*32+q)*128 + c]
__global__ void cvt_ktile(const float* __restrict__ src, u16* __restrict__ dst,
                          int coff) {
  const int i = blockIdx.x * blockDim.x + threadIdx.x;  // over 512*128
  if (i < 512 * 128) {
    const int k = i >> 7, c = i & 127;
    dst[(k >> 5) * 8192 + (c + coff) * 32 + (k & 31)] = f2bf(src[i]);
  }
}

// ---------------- K0: LN stream: feats fp32 -> xn bf16 (swizzled chunks) ---
// grid 8192 blocks x 256 thr (4 waves), wave owns 8 rows. r9's PROVEN
// phase-1 (reg loads + 64-lane butterfly + LN in regs), writing each row's
// 16B chunk to HBM at chunk index lane^(row&7) (pre-swizzled source so the
// GEMM kernel's linear DMA + swizzled ds_read sees the r9 LDS layout).
// No LDS, no barriers: waves free-run, TLP hides chain latency.
__global__ __launch_bounds__(256, 4) void k0_lnstream(
    const float* __restrict__ feats, const float* __restrict__ lng,
    const float* __restrict__ lnb, u16* __restrict__ xn) {
  const int wave = threadIdx.x >> 6, lane = threadIdx.x & 63;
  const long long row0 = (long long)blockIdx.x * 32 + wave * 8;

  const float4 g0 = *(const float4*)&lng[lane * 8];
  const float4 g1 = *(const float4*)&lng[lane * 8 + 4];
  const float4 bb0 = *(const float4*)&lnb[lane * 8];
  const float4 bb1 = *(const float4*)&lnb[lane * 8 + 4];

  const float* base = feats + row0 * 512 + lane * 8;
  float4 x0[8], x1[8];
#pragma unroll
  for (int i = 0; i < 8; ++i) {
    x0[i] = ((const float4*)(base + i * 512))[0];
    x1[i] = ((const float4*)(base + i * 512))[1];
  }
#pragma unroll
  for (int i = 0; i < 8; ++i) {
    const long long grow = row0 + i;
    float s = (x0[i].x + x0[i].y) + (x0[i].z + x0[i].w) +
              (x1[i].x + x1[i].y) + (x1[i].z + x1[i].w);
    float q = x0[i].x * x0[i].x + x0[i].y * x0[i].y + x0[i].z * x0[i].z +
              x0[i].w * x0[i].w + x1[i].x * x1[i].x + x1[i].y * x1[i].y +
              x1[i].z * x1[i].z + x1[i].w * x1[i].w;
#pragma unroll
    for (int m = 1; m < 64; m <<= 1) {
      s += __shfl_xor(s, m);
      q += __shfl_xor(q, m);
    }
    const float mu = s * (1.f / 512.f);
    const float rstd = rsqrtf(q * (1.f / 512.f) - mu * mu + LNEPS);
    const float y0 = (x0[i].x - mu) * rstd * g0.x + bb0.x;
    const float y1 = (x0[i].y - mu) * rstd * g0.y + bb0.y;
    const float y2 = (x0[i].z - mu) * rstd * g0.z + bb0.z;
    const float y3 = (x0[i].w - mu) * rstd * g0.w + bb0.w;
    const float y4 = (x1[i].x - mu) * rstd * g1.x + bb1.x;
    const float y5 = (x1[i].y - mu) * rstd * g1.y + bb1.y;
    const float y6 = (x1[i].z - mu) * rstd * g1.z + bb1.z;
    const float y7 = (x1[i].w - mu) * rstd * g1.w + bb1.w;
    uint4 w;
    w.x = pk2(y0, y1);
    w.y = pk2(y2, y3);
    w.z = pk2(y4, y5);
    w.w = pk2(y6, y7);
    *(uint4*)((char*)xn + grow * 1024 +
              ((lane * 16) ^ (((int)grow & 7) << 4))) = w;
  }
}

// ---------------- K1: GEMM xn(bf16) @ Wcat -> k, v^T ----------------
// grid 8192 blocks x 256 thr (4 waves). Block: 32 rows x 256 cols, K=512.
// Phase 0: linear DMA of the pre-swizzled bf16 tile (32 x 1KB).
// GEMM/epilogue/packs = r9 verbatim. 32KB LDS -> 5 blocks/CU.
__global__ __launch_bounds__(256, 5) void k1_gemm(
    const u16* __restrict__ xn, const u16* __restrict__ Wcat,
    const float* __restrict__ bk, const float* __restrict__ bv,
    u16* __restrict__ kbuf, u16* __restrict__ vt) {
  __shared__ alignas(16) union {
    u16 a[32 * 512];                                    // 32768 B (GEMM A)
    struct { u16 kq[32 * 136]; float c[128 * 36]; } e;  // 8704+18432 B
  } sm;
  const int tid = threadIdx.x;
  const int wave = tid >> 6, lane = tid & 63;
  const int lq = lane >> 4, lm = lane & 15;
  const long long row0 = (long long)blockIdx.x * 32;

  // ---- phase 0: DMA bf16 tile (8 x 1KB per wave) ----
  {
    const char* gsrc = (const char*)xn + row0 * 1024;
#pragma unroll
    for (int jj = 0; jj < 8; ++jj) {
      const int inst = wave * 8 + jj;
      gload_lds16(gsrc + inst * 1024 + lane * 16, (char*)sm.a + inst * 1024);
    }
  }
  __syncthreads();

  // ---- GEMM: wave = col-quarter cq; rows 0..31 (2 m-tiles) ----
  const int cq = wave;
  f32x4 acc[2][4];
  {
    const f32x4 z4 = {0.f, 0.f, 0.f, 0.f};
#pragma unroll
    for (int m = 0; m < 2; ++m)
#pragma unroll
      for (int n = 0; n < 4; ++n) acc[m][n] = z4;
  }
  const u16* wb = Wcat + (cq * 64 + lm) * 32 + lq * 8;  // k-slab base
#pragma unroll 4
  for (int ks = 0; ks < 16; ++ks) {
    bf16x8 a[2], b[4];
#pragma unroll
    for (int mi = 0; mi < 2; ++mi) {
      const int row = mi * 16 + lm;
      a[mi] = *(const bf16x8*)((const char*)sm.a + row * 1024 +
                               ((ks * 64 + lq * 16) ^ ((row & 7) << 4)));
    }
#pragma unroll
    for (int nt = 0; nt < 4; ++nt)
      b[nt] = *(const bf16x8*)&wb[ks * 8192 + nt * 512];
#pragma unroll
    for (int mi = 0; mi < 2; ++mi)
#pragma unroll
      for (int nt = 0; nt < 4; ++nt)
        acc[mi][nt] = mfma16(a[mi], b[nt], acc[mi][nt]);
  }
  __syncthreads();  // A-tile dead; union becomes epilogue staging

  // ---- epilogue staging: k (bf16) and v (fp32, transposed) into LDS ----
  if (cq < 2) {
#pragma unroll
    for (int nt = 0; nt < 4; ++nt) {
      const int col = cq * 64 + nt * 16 + lm;
      const float bias = bk[col];
#pragma unroll
      for (int mi = 0; mi < 2; ++mi)
#pragma unroll
        for (int r = 0; r < 4; ++r) {
          const int row = mi * 16 + lq * 4 + r;
          sm.e.kq[row * 136 + col] = f2bf(acc[mi][nt][r] + bias);
        }
    }
  } else {
#pragma unroll
    for (int nt = 0; nt < 4; ++nt) {
      const int d = (cq - 2) * 64 + nt * 16 + lm;
      const float bias = bv[d];
#pragma unroll
      for (int mi = 0; mi < 2; ++mi)
#pragma unroll
        for (int r = 0; r < 4; ++r) {
          const int row = mi * 16 + lq * 4 + r;
          sm.e.c[d * 36 + row] = acc[mi][nt][r] + bias;
        }
    }
  }
  __syncthreads();

  const long long bidx = row0 >> 12;
  const int nbase = (int)(row0 & 4095);
  // ---- pack k: 32 rows x 128 cols, coalesced 16B stores ----
  {
    const int row = tid >> 3, c0 = (tid & 7) * 16;
    const u16* sp = &sm.e.kq[row * 136 + c0];
    u16* dst = kbuf + (row0 + row) * 128 + c0;
    *(uint4*)(dst) = *(const uint4*)(sp);
    *(uint4*)(dst + 8) = *(const uint4*)(sp + 8);
  }
  // ---- pack v^T: [d][N] bf16 ----
  {
    const int d = tid >> 1, nh = (tid & 1) * 16;
    const float* cp = &sm.e.c[d * 36 + nh];
    u16* dst = vt + (bidx * 128 + d) * 4096 + nbase + nh;
#pragma unroll
    for (int q = 0; q < 2; ++q) {
      uint4 p;
      p.x = pk2(cp[q * 8 + 0], cp[q * 8 + 1]);
      p.y = pk2(cp[q * 8 + 2], cp[q * 8 + 3]);
      p.z = pk2(cp[q * 8 + 4], cp[q * 8 + 5]);
      p.w = pk2(cp[q * 8 + 6], cp[q * 8 + 7]);
      *(uint4*)(dst + q * 8) = p;
    }
  }
}

// ---------------- K3: q-proj + dots + slot-softmax + P@v partials ----------
// grid 512 blocks (64 batches x 8 chunks), 256 thr. Wave handles 128 tokens.
__global__ __launch_bounds__(256) void k3_attn(
    const float* __restrict__ slots_in, const int* __restrict__ is_first, int iter,
    const float* __restrict__ lsg, const float* __restrict__ lsb,
    const u16* __restrict__ Wqt, const float* __restrict__ bq,
    const u16* __restrict__ kbuf, const u16* __restrict__ vt,
    float* __restrict__ updp, float* __restrict__ rsp) {
  const int ni = (*is_first) ? 3 : 2;
  if (iter >= ni) return;
  __shared__ alignas(16) u16 slns[16 * 136];
  __shared__ alignas(16) u16 qlds[16 * 136];
  __shared__ alignas(16) u16 plds[4][640];
  __shared__ alignas(16) float ures[4][16 * 128];
  __shared__ float rres[4][16];
  const int tid = threadIdx.x;
  const int wave = tid >> 6, lane = tid & 63;
  const int lq = lane >> 4, lm = lane & 15;
  const int b = blockIdx.x >> 3, chunk = blockIdx.x & 7;

  // LN(slots) by wave 0
  if (wave == 0) {
    const int s = lane >> 2, cc = (lane & 3) * 32;
    const float* sp = slots_in + ((long long)b * 16 + s) * 128 + cc;
    float x[32];
    float sum = 0.f, sq = 0.f;
#pragma unroll
    for (int j = 0; j < 32; ++j) { x[j] = sp[j]; sum += x[j]; sq += x[j] * x[j]; }
    sum += __shfl_xor(sum, 1); sum += __shfl_xor(sum, 2);
    sq  += __shfl_xor(sq, 1);  sq  += __shfl_xor(sq, 2);
    const float mu = sum * (1.f / 128.f);
    const float rstd = rsqrtf(sq * (1.f / 128.f) - mu * mu + LNEPS);
#pragma unroll
    for (int j = 0; j < 32; ++j) {
      const int c = cc + j;
      slns[s * 136 + c] = f2bf((x[j] - mu) * rstd * lsg[c] + lsb[c]);
    }
  }
  __syncthreads();
  // q = LN(slots) @ Wq + bq ; wave computes cols [wave*32, wave*32+32)
  {
    f32x4 qa0 = {0.f, 0.f, 0.f, 0.f}, qa1 = {0.f, 0.f, 0.f, 0.f};
#pragma unroll
    for (int ks = 0; ks < 4; ++ks) {
      const bf16x8 af = *(const bf16x8*)&slns[lm * 136 + ks * 32 + lq * 8];
      const bf16x8 b0 = *(const bf16x8*)&Wqt[(wave * 32 + lm) * 128 + ks * 32 + lq * 8];
      const bf16x8 b1 = *(const bf16x8*)&Wqt[(wave * 32 + 16 + lm) * 128 + ks * 32 + lq * 8];
      qa0 = mfma16(af, b0, qa0);
      qa1 = mfma16(af, b1, qa1);
    }
#pragma unroll
    for (int r = 0; r < 4; ++r) {
      const int s = lq * 4 + r;
      const int c0 = wave * 32 + lm, c1 = c0 + 16;
      qlds[s * 136 + c0] = f2bf(qa0[r] + bq[c0]);
      qlds[s * 136 + c1] = f2bf(qa1[r] + bq[c1]);
    }
  }
  __syncthreads();

  bf16x8 qf[4];
#pragma unroll
  for (int ks = 0; ks < 4; ++ks)
    qf[ks] = *(const bf16x8*)&qlds[lm * 136 + ks * 32 + lq * 8];

  float rs0 = 0.f, rs1 = 0.f, rs2 = 0.f, rs3 = 0.f;
  const f32x4 z4 = {0.f, 0.f, 0.f, 0.f};
  f32x4 uacc[8];
#pragma unroll
  for (int i = 0; i < 8; ++i) uacc[i] = z4;
  u16* pw = plds[wave];
  const int n0w = chunk * 512 + wave * 128;
  const u16* kb = kbuf + (long long)b * 4096 * 128;
  const u16* vb = vt + (long long)b * 128 * 4096;

  for (int g = 0; g < 4; ++g) {
    const int nb = n0w + g * 32;
#pragma unroll
    for (int sub = 0; sub < 2; ++sub) {
      f32x4 dot = z4;
      const u16* kr = kb + (long long)(nb + sub * 16 + lm) * 128 + lq * 8;
#pragma unroll
      for (int ks = 0; ks < 4; ++ks)
        dot = mfma16(qf[ks], *(const bf16x8*)&kr[ks * 32], dot);
      const float d0 = dot[0] * SCALE, d1 = dot[1] * SCALE;
      const float d2 = dot[2] * SCALE, d3 = dot[3] * SCALE;
      float m = fmaxf(fmaxf(d0, d1), fmaxf(d2, d3));
      m = fmaxf(m, __shfl_xor(m, 16));
      m = fmaxf(m, __shfl_xor(m, 32));
      const float e0 = __expf(d0 - m), e1 = __expf(d1 - m);
      const float e2 = __expf(d2 - m), e3 = __expf(d3 - m);
      float ss = e0 + e1 + e2 + e3;
      ss += __shfl_xor(ss, 16);
      ss += __shfl_xor(ss, 32);
      const float inv = 1.f / ss;
      const float p0 = e0 * inv + ATTN_EPS, p1 = e1 * inv + ATTN_EPS;
      const float p2 = e2 * inv + ATTN_EPS, p3 = e3 * inv + ATTN_EPS;
      rs0 += p0; rs1 += p1; rs2 += p2; rs3 += p3;
      const int nc = sub * 16 + lm;
      pw[(lq * 4 + 0) * 40 + nc] = f2bf(p0);
      pw[(lq * 4 + 1) * 40 + nc] = f2bf(p1);
      pw[(lq * 4 + 2) * 40 + nc] = f2bf(p2);
      pw[(lq * 4 + 3) * 40 + nc] = f2bf(p3);
    }
    const bf16x8 pa = *(const bf16x8*)&pw[lm * 40 + lq * 8];
    const u16* vr = vb + (long long)lm * 4096 + nb + lq * 8;
#pragma unroll
    for (int dt = 0; dt < 8; ++dt)
      uacc[dt] = mfma16(pa, *(const bf16x8*)&vr[(long long)dt * 16 * 4096], uacc[dt]);
  }
  // rowsum reduce across the 16 lanes of each quarter
#pragma unroll
  for (int msk = 1; msk < 16; msk <<= 1) {
    rs0 += __shfl_xor(rs0, msk); rs1 += __shfl_xor(rs1, msk);
    rs2 += __shfl_xor(rs2, msk); rs3 += __shfl_xor(rs3, msk);
  }
#pragma unroll
  for (int dt = 0; dt < 8; ++dt)
#pragma unroll
    for (int r = 0; r < 4; ++r)
      ures[wave][(lq * 4 + r) * 128 + dt * 16 + lm] = uacc[dt][r];
  if (lm == 0) {
    rres[wave][lq * 4 + 0] = rs0; rres[wave][lq * 4 + 1] = rs1;
    rres[wave][lq * 4 + 2] = rs2; rres[wave][lq * 4 + 3] = rs3;
  }
  __syncthreads();
  {
    const int e0 = tid * 8;
    float* dst = updp + (long long)(b * 8 + chunk) * 2048 + e0;
#pragma unroll
    for (int e = 0; e < 8; ++e)
      dst[e] = ures[0][e0 + e] + ures[1][e0 + e] + ures[2][e0 + e] + ures[3][e0 + e];
  }
  if (tid < 16)
    rsp[(b * 8 + chunk) * 16 + tid] =
        rres[0][tid] + rres[1][tid] + rres[2][tid] + rres[3][tid];
}

// ---------------- K4: reduce partials + GRU + MLP -> new slots -------------
// grid 64 blocks (batch), 256 thr.
__global__ __launch_bounds__(256) void k4_update(
    const float* __restrict__ slots_in, const int* __restrict__ is_first, int iter,
    const float* __restrict__ updp, const float* __restrict__ rsp,
    const u16* __restrict__ Wih, const u16* __restrict__ Whh,
    const float* __restrict__ bih, const float* __restrict__ bhh,
    const float* __restrict__ lmg, const float* __restrict__ lmb,
    const u16* __restrict__ W1t, const float* __restrict__ b1,
    const u16* __restrict__ W2t, const float* __restrict__ b2,
    float* __restrict__ slots_out, float* __restrict__ dout) {
  const int ni = (*is_first) ? 3 : 2;
  if (iter >= ni) return;
  const bool last = (iter == ni - 1);
  __shared__ float g_ih[16 * 392];
  __shared__ float g_hh[16 * 392];
  __shared__ alignas(16) float hsp[16 * 128];
  __shared__ float rsum[16];
  __shared__ alignas(16) u16 ubf[16 * 136];
  __shared__ alignas(16) u16 xbf[16 * 136];
  __shared__ alignas(16) u16 hidbf[16 * 520];
  const int tid = threadIdx.x;
  const int wave = tid >> 6, lane = tid & 63;
  const int lq = lane >> 4, lm = lane & 15;
  const int b = blockIdx.x;
  const int es = tid >> 4;         // slot row for this thread's 8 elems
  const int ej = (tid & 15) * 8;   // col start

  // slots_prev -> hsp (fp32) and xbf (bf16)
  {
    const float* sp = slots_in + (long long)b * 2048 + tid * 8;
    const float4 a = ((const float4*)sp)[0], c = ((const float4*)sp)[1];
    *(float4*)&hsp[tid * 8] = a;
    *(float4*)&hsp[tid * 8 + 4] = c;
    uint4 p;
    p.x = pk2(a.x, a.y);
    p.y = pk2(a.z, a.w);
    p.z = pk2(c.x, c.y);
    p.w = pk2(c.z, c.w);
    *(uint4*)&xbf[es * 136 + ej] = p;
  }
  if (tid < 16) {
    float s = 0.f;
    for (int p = 0; p < 8; ++p) s += rsp[(b * 8 + p) * 16 + tid];
    rsum[tid] = s;
  }
  __syncthreads();
  // reduce updates partials, normalize by rowsum -> ubf (bf16)
  {
    float acc[8];
#pragma unroll
    for (int e = 0; e < 8; ++e) acc[e] = 0.f;
    for (int p = 0; p < 8; ++p) {
      const float* src = updp + (long long)(b * 8 + p) * 2048 + tid * 8;
      const float4 x = ((const float4*)src)[0], y = ((const float4*)src)[1];
      acc[0] += x.x; acc[1] += x.y; acc[2] += x.z; acc[3] += x.w;
      acc[4] += y.x; acc[5] += y.y; acc[6] += y.z; acc[7] += y.w;
    }
    const float inv = 1.f / rsum[es];
    uint4 p;
    p.x = pk2(acc[0] * inv, acc[1] * inv);
    p.y = pk2(acc[2] * inv, acc[3] * inv);
    p.z = pk2(acc[4] * inv, acc[5] * inv);
    p.w = pk2(acc[6] * inv, acc[7] * inv);
    *(uint4*)&ubf[es * 136 + ej] = p;
  }
  __syncthreads();
  // gi = u @ Wih^T + bih ; gh = h @ Whh^T + bhh  (wave: cols wave*96..+96)
  {
    bf16x8 ua[4], ha[4];
#pragma unroll
    for (int ks = 0; ks < 4; ++ks) {
      ua[ks] = *(const bf16x8*)&ubf[lm * 136 + ks * 32 + lq * 8];
      ha[ks] = *(const bf16x8*)&xbf[lm * 136 + ks * 32 + lq * 8];
    }
    const f32x4 z4 = {0.f, 0.f, 0.f, 0.f};
    f32x4 gi[6], gh[6];
#pragma unroll
    for (int t = 0; t < 6; ++t) { gi[t] = z4; gh[t] = z4; }
#pragma unroll
    for (int ks = 0; ks < 4; ++ks)
#pragma unroll
      for (int t = 0; t < 6; ++t) {
        const int col = wave * 96 + t * 16 + lm;
        gi[t] = mfma16(ua[ks], *(const bf16x8*)&Wih[(long long)col * 128 + ks * 32 + lq * 8], gi[t]);
        gh[t] = mfma16(ha[ks], *(const bf16x8*)&Whh[(long long)col * 128 + ks * 32 + lq * 8], gh[t]);
      }
#pragma unroll
    for (int t = 0; t < 6; ++t)
#pragma unroll
      for (int r = 0; r < 4; ++r) {
        const int col = wave * 96 + t * 16 + lm, s = lq * 4 + r;
        g_ih[s * 392 + col] = gi[t][r] + bih[col];
        g_hh[s * 392 + col] = gh[t][r] + bhh[col];
      }
  }
  __syncthreads();
  // gates (elementwise), h overwrites hsp
  {
#pragma unroll
    for (int e = 0; e < 8; ++e) {
      const int j = ej + e;
      const float sr = g_ih[es * 392 + j] + g_hh[es * 392 + j];
      const float sz = g_ih[es * 392 + 128 + j] + g_hh[es * 392 + 128 + j];
      const float r = 1.f / (1.f + __expf(-sr));
      const float z = 1.f / (1.f + __expf(-sz));
      const float n = tanhf(g_ih[es * 392 + 256 + j] + r * g_hh[es * 392 + 256 + j]);
      hsp[es * 128 + j] = (1.f - z) * n + z * hsp[es * 128 + j];
    }
  }
  __syncthreads();
  // LN(h) -> xbf (wave 0)
  if (wave == 0) {
    const int s = lane >> 2, cc = (lane & 3) * 32;
    float x[32];
    float sum = 0.f, sq = 0.f;
#pragma unroll
    for (int j = 0; j < 32; ++j) {
      x[j] = hsp[s * 128 + cc + j]; sum += x[j]; sq += x[j] * x[j];
    }
    sum += __shfl_xor(sum, 1); sum += __shfl_xor(sum, 2);
    sq  += __shfl_xor(sq, 1);  sq  += __shfl_xor(sq, 2);
    const float mu = sum * (1.f / 128.f);
    const float rstd = rsqrtf(sq * (1.f / 128.f) - mu * mu + LNEPS);
#pragma unroll
    for (int j = 0; j < 32; ++j) {
      const int c = cc + j;
      xbf[s * 136 + c] = f2bf((x[j] - mu) * rstd * lmg[c] + lmb[c]);
    }
  }
  __syncthreads();
  // MLP1: hid = relu(LN(h) @ W1 + b1)   (wave: cols wave*128..+128)
  {
    bf16x8 xa[4];
#pragma unroll
    for (int ks = 0; ks < 4; ++ks)
      xa[ks] = *(const bf16x8*)&xbf[lm * 136 + ks * 32 + lq * 8];
    const f32x4 z4 = {0.f, 0.f, 0.f, 0.f};
    f32x4 m1[8];
#pragma unroll
    for (int t = 0; t < 8; ++t) m1[t] = z4;
#pragma unroll
    for (int ks = 0; ks < 4; ++ks)
#pragma unroll
      for (int t = 0; t < 8; ++t) {
        const int col = wave * 128 + t * 16 + lm;
        m1[t] = mfma16(xa[ks], *(const bf16x8*)&W1t[(long long)col * 128 + ks * 32 + lq * 8], m1[t]);
      }
#pragma unroll
    for (int t = 0; t < 8; ++t)
#pragma unroll
      for (int r = 0; r < 4; ++r) {
        const int col = wave * 128 + t * 16 + lm, s = lq * 4 + r;
        hidbf[s * 520 + col] = f2bf(fmaxf(m1[t][r] + b1[col], 0.f));
      }
  }
  __syncthreads();
  // MLP2 + residual: out = h + hid @ W2 + b2  (wave: cols wave*32..+32)
  {
    const f32x4 z4 = {0.f, 0.f, 0.f, 0.f};
    f32x4 m2a = z4, m2b = z4;
#pragma unroll
    for (int ks = 0; ks < 16; ++ks) {
      const bf16x8 xa = *(const bf16x8*)&hidbf[lm * 520 + ks * 32 + lq * 8];
      m2a = mfma16(xa, *(const bf16x8*)&W2t[(long long)(wave * 32 + lm) * 512 + ks * 32 + lq * 8], m2a);
      m2b = mfma16(xa, *(const bf16x8*)&W2t[(long long)(wave * 32 + 16 + lm) * 512 + ks * 32 + lq * 8], m2b);
    }
#pragma unroll
    for (int r = 0; r < 4; ++r) {
      const int s = lq * 4 + r;
      const int c0 = wave * 32 + lm, c1 = c0 + 16;
      const float o0 = m2a[r] + b2[c0] + hsp[s * 128 + c0];
      const float o1 = m2b[r] + b2[c1] + hsp[s * 128 + c1];
      float* o = slots_out + ((long long)b * 16 + s) * 128;
      o[c0] = o0; o[c1] = o1;
      if (last) {
        float* d = dout + ((long long)b * 16 + s) * 128;
        d[c0] = o0; d[c1] = o1;
      }
    }
  }
}

extern "C" void kernel_launch(void* const* d_in, const int* in_sizes, int n_in,
                              void* d_out, int out_size, void* d_ws, size_t ws_size,
                              hipStream_t stream) {
  (void)in_sizes; (void)n_in; (void)out_size; (void)ws_size;
  const float* feats    = (const float*)d_in[0];
  const float* slots0   = (const float*)d_in[1];
  const int*   is_first = (const int*)d_in[2];
  const float* ln_in_g  = (const float*)d_in[3];
  const float* ln_in_b  = (const float*)d_in[4];
  const float* ln_sl_g  = (const float*)d_in[5];
  const float* ln_sl_b  = (const float*)d_in[6];
  const float* ln_ml_g  = (const float*)d_in[7];
  const float* ln_ml_b  = (const float*)d_in[8];
  const float* Wq  = (const float*)d_in[9];
  const float* bq  = (const float*)d_in[10];
  const float* Wk  = (const float*)d_in[11];
  const float* bk  = (const float*)d_in[12];
  const float* Wv  = (const float*)d_in[13];
  const float* bv  = (const float*)d_in[14];
  const float* Wih_f = (const float*)d_in[15];
  const float* Whh_f = (const float*)d_in[16];
  const float* bih = (const float*)d_in[17];
  const float* bhh = (const float*)d_in[18];
  const float* W1  = (const float*)d_in[19];
  const float* b1  = (const float*)d_in[20];
  const float* W2  = (const float*)d_in[21];
  const float* b2  = (const float*)d_in[22];

  char* ws = (char*)d_ws;
  size_t off = 0;
  auto alloc = [&](size_t bytes) -> void* {
    void* p = ws + off;
    off = (off + bytes + 255) & ~(size_t)255;
    return p;
  };
  u16* kbuf   = (u16*)alloc((size_t)64 * 4096 * 128 * 2);
  u16* vt     = (u16*)alloc((size_t)64 * 4096 * 128 * 2);
  u16* xn     = (u16*)alloc((size_t)64 * 4096 * 512 * 2);
  u16* Wcat   = (u16*)alloc((size_t)16 * 256 * 32 * 2);
  u16* Wqt    = (u16*)alloc((size_t)128 * 128 * 2);
  u16* Wih    = (u16*)alloc((size_t)384 * 128 * 2);
  u16* Whh    = (u16*)alloc((size_t)384 * 128 * 2);
  u16* W1t    = (u16*)alloc((size_t)512 * 128 * 2);
  u16* W2t    = (u16*)alloc((size_t)128 * 512 * 2);
  float* updp = (float*)alloc((size_t)64 * 8 * 2048 * 4);
  float* rsp  = (float*)alloc((size_t)64 * 8 * 16 * 4);
  float* slA  = (float*)alloc((size_t)64 * 2048 * 4);
  float* slB  = (float*)alloc((size_t)64 * 2048 * 4);

  // weight conversions (bf16, layouts for MFMA B-fragments)
  cvt_ktile<<<256, 256, 0, stream>>>(Wk, Wcat, 0);
  cvt_ktile<<<256, 256, 0, stream>>>(Wv, Wcat, 128);
  cvt_kernel<<<64, 256, 0, stream>>>(Wq, Wqt, 128, 128, 1);
  cvt_kernel<<<64, 256, 0, stream>>>(Wih_f, Wih, 384, 128, 0);
  cvt_kernel<<<64, 256, 0, stream>>>(Whh_f, Whh, 384, 128, 0);
  cvt_kernel<<<64, 256, 0, stream>>>(W1, W1t, 128, 512, 1);
  cvt_kernel<<<64, 256, 0, stream>>>(W2, W2t, 512, 128, 1);

  k0_lnstream<<<8192, 256, 0, stream>>>(feats, ln_in_g, ln_in_b, xn);
  k1_gemm<<<8192, 256, 0, stream>>>(xn, Wcat, bk, bv, kbuf, vt);

  float* bufs[2] = {slA, slB};
  for (int it = 0; it < 3; ++it) {
    const float* sin_ = (it == 0) ? slots0 : bufs[(it + 1) & 1];
    float* sout = bufs[it & 1];
    k3_attn<<<512, 256, 0, stream>>>(sin_, is_first, it, ln_sl_g, ln_sl_b, Wqt, bq,
                                     kbuf, vt, updp, rsp);
    k4_update<<<64, 256, 0, stream>>>(sin_, is_first, it, updp, rsp, Wih, Whh,
                                      bih, bhh, ln_ml_g, ln_ml_b, W1t, b1, W2t, b2,
                                      sout, (float*)d_out);
  }
}

// Round 13
// 394.279 us; speedup vs baseline: 1.3618x; 1.2984x over previous
//
#include <hip/hip_runtime.h>

typedef __attribute__((ext_vector_type(4))) float f32x4;
typedef __attribute__((ext_vector_type(8))) short bf16x8;
typedef unsigned short u16;

#define LNEPS 1e-3f
#define ATTN_EPS 1e-8f
#define SCALE 0.044194173824159216f  // 512^-0.5

__device__ __forceinline__ u16 f2bf(float f) {
  union { float f; unsigned u; } v; v.f = f;
  unsigned r = v.u + 0x7fffu + ((v.u >> 16) & 1u);
  return (u16)(r >> 16);
}
__device__ __forceinline__ float bf2f(unsigned u) {
  union { float f; unsigned u; } v; v.u = (u & 0xffffu) << 16; return v.f;
}
__device__ __forceinline__ f32x4 mfma16(bf16x8 a, bf16x8 b, f32x4 c) {
  return __builtin_amdgcn_mfma_f32_16x16x32_bf16(a, b, c, 0, 0, 0);
}
__device__ __forceinline__ unsigned pk2(float a, float b) {
  return (unsigned)f2bf(a) | ((unsigned)f2bf(b) << 16);
}

// ---------------- single fused weight-conversion kernel ----------------
// ranges: [0,64K) Wk->ktile(0) | [64K,128K) Wv->ktile(128) | Wq trans |
// Wih copy | Whh copy | W1 trans(128x512) | W2 trans(512x128)
__global__ void cvt_all(
    const float* __restrict__ Wk, const float* __restrict__ Wv,
    const float* __restrict__ Wq, const float* __restrict__ Wih_f,
    const float* __restrict__ Whh_f, const float* __restrict__ W1,
    const float* __restrict__ W2, u16* __restrict__ Wcat,
    u16* __restrict__ Wqt, u16* __restrict__ Wih, u16* __restrict__ Whh,
    u16* __restrict__ W1t, u16* __restrict__ W2t) {
  const int i = blockIdx.x * blockDim.x + threadIdx.x;
  if (i < 65536) {
    const int k = i >> 7, c = i & 127;
    Wcat[(k >> 5) * 8192 + c * 32 + (k & 31)] = f2bf(Wk[i]);
  } else if (i < 131072) {
    const int j = i - 65536;
    const int k = j >> 7, c = j & 127;
    Wcat[(k >> 5) * 8192 + (c + 128) * 32 + (k & 31)] = f2bf(Wv[j]);
  } else if (i < 147456) {
    const int j = i - 131072;
    const int r = j >> 7, c = j & 127;
    Wqt[c * 128 + r] = f2bf(Wq[j]);
  } else if (i < 196608) {
    const int j = i - 147456;
    Wih[j] = f2bf(Wih_f[j]);
  } else if (i < 245760) {
    const int j = i - 196608;
    Whh[j] = f2bf(Whh_f[j]);
  } else if (i < 311296) {
    const int j = i - 245760;
    const int r = j / 512, c = j - r * 512;
    W1t[c * 128 + r] = f2bf(W1[j]);
  } else if (i < 376832) {
    const int j = i - 311296;
    const int r = j >> 7, c = j & 127;
    W2t[c * 512 + r] = f2bf(W2[j]);
  }
}

// ---------------- K1: LN(features) -> k,v projections (r9 structure) ------
// grid 8192 blocks x 256 thr (4 waves). Block: 32 rows x 256 cols, K=512.
// launch_bounds(256,4): VGPR cap 128 (was 102) so phase-1's 16 float4
// loads can stay live in flight instead of serializing at 60 VGPR.
// Phase 1 = PROVEN butterfly+LN-in-regs. GEMM B via k-slab layout.
__global__ __launch_bounds__(256, 4) void k1_lnproj(
    const float* __restrict__ feats, const float* __restrict__ lng,
    const float* __restrict__ lnb, const u16* __restrict__ Wcat,
    const float* __restrict__ bk, const float* __restrict__ bv,
    u16* __restrict__ kbuf, u16* __restrict__ vt) {
  __shared__ alignas(16) union {
    u16 a[32 * 512];                                    // 32768 B (GEMM A)
    struct { u16 kq[32 * 136]; float c[128 * 36]; } e;  // 8704+18432 B
  } sm;
  const int tid = threadIdx.x;
  const int wave = tid >> 6, lane = tid & 63;
  const int lq = lane >> 4, lm = lane & 15;
  const long long row0 = (long long)blockIdx.x * 32;

  // LN params for this lane's 8 columns (uniform across rows)
  const float4 g0 = *(const float4*)&lng[lane * 8];
  const float4 g1 = *(const float4*)&lng[lane * 8 + 4];
  const float4 bb0 = *(const float4*)&lnb[lane * 8];
  const float4 bb1 = *(const float4*)&lnb[lane * 8 + 4];

  // ---- phase 1: load 8 rows/wave + butterfly stats + LN in regs ----
  {
    const float* base = feats + (row0 + wave * 8) * 512 + lane * 8;
    float4 x0[8], x1[8];
#pragma unroll
    for (int i = 0; i < 8; ++i) {
      x0[i] = ((const float4*)(base + i * 512))[0];
      x1[i] = ((const float4*)(base + i * 512))[1];
    }
#pragma unroll
    for (int i = 0; i < 8; ++i) {
      const int r = wave * 8 + i;
      float s = (x0[i].x + x0[i].y) + (x0[i].z + x0[i].w) +
                (x1[i].x + x1[i].y) + (x1[i].z + x1[i].w);
      float q = x0[i].x * x0[i].x + x0[i].y * x0[i].y + x0[i].z * x0[i].z +
                x0[i].w * x0[i].w + x1[i].x * x1[i].x + x1[i].y * x1[i].y +
                x1[i].z * x1[i].z + x1[i].w * x1[i].w;
#pragma unroll
      for (int m = 1; m < 64; m <<= 1) {
        s += __shfl_xor(s, m);
        q += __shfl_xor(q, m);
      }
      const float mu = s * (1.f / 512.f);
      const float rstd = rsqrtf(q * (1.f / 512.f) - mu * mu + LNEPS);
      const float y0 = (x0[i].x - mu) * rstd * g0.x + bb0.x;
      const float y1 = (x0[i].y - mu) * rstd * g0.y + bb0.y;
      const float y2 = (x0[i].z - mu) * rstd * g0.z + bb0.z;
      const float y3 = (x0[i].w - mu) * rstd * g0.w + bb0.w;
      const float y4 = (x1[i].x - mu) * rstd * g1.x + bb1.x;
      const float y5 = (x1[i].y - mu) * rstd * g1.y + bb1.y;
      const float y6 = (x1[i].z - mu) * rstd * g1.z + bb1.z;
      const float y7 = (x1[i].w - mu) * rstd * g1.w + bb1.w;
      uint4 w;
      w.x = pk2(y0, y1);
      w.y = pk2(y2, y3);
      w.z = pk2(y4, y5);
      w.w = pk2(y6, y7);
      *(uint4*)((char*)sm.a + r * 1024 + ((lane * 16) ^ ((r & 7) << 4))) = w;
    }
  }
  __syncthreads();

  // ---- GEMM: wave = col-quarter cq; rows 0..31 (2 m-tiles) ----
  const int cq = wave;
  f32x4 acc[2][4];
  {
    const f32x4 z4 = {0.f, 0.f, 0.f, 0.f};
#pragma unroll
    for (int m = 0; m < 2; ++m)
#pragma unroll
      for (int n = 0; n < 4; ++n) acc[m][n] = z4;
  }
  const u16* wb = Wcat + (cq * 64 + lm) * 32 + lq * 8;  // k-slab base
#pragma unroll 4
  for (int ks = 0; ks < 16; ++ks) {
    bf16x8 a[2], b[4];
#pragma unroll
    for (int mi = 0; mi < 2; ++mi) {
      const int row = mi * 16 + lm;
      a[mi] = *(const bf16x8*)((const char*)sm.a + row * 1024 +
                               ((ks * 64 + lq * 16) ^ ((row & 7) << 4)));
    }
#pragma unroll
    for (int nt = 0; nt < 4; ++nt)
      b[nt] = *(const bf16x8*)&wb[ks * 8192 + nt * 512];
#pragma unroll
    for (int mi = 0; mi < 2; ++mi)
#pragma unroll
      for (int nt = 0; nt < 4; ++nt)
        acc[mi][nt] = mfma16(a[mi], b[nt], acc[mi][nt]);
  }
  __syncthreads();  // A-tile dead; union becomes epilogue staging

  // ---- epilogue staging: k (bf16) and v (fp32, transposed) into LDS ----
  if (cq < 2) {
#pragma unroll
    for (int nt = 0; nt < 4; ++nt) {
      const int col = cq * 64 + nt * 16 + lm;
      const float bias = bk[col];
#pragma unroll
      for (int mi = 0; mi < 2; ++mi)
#pragma unroll
        for (int r = 0; r < 4; ++r) {
          const int row = mi * 16 + lq * 4 + r;
          sm.e.kq[row * 136 + col] = f2bf(acc[mi][nt][r] + bias);
        }
    }
  } else {
#pragma unroll
    for (int nt = 0; nt < 4; ++nt) {
      const int d = (cq - 2) * 64 + nt * 16 + lm;
      const float bias = bv[d];
#pragma unroll
      for (int mi = 0; mi < 2; ++mi)
#pragma unroll
        for (int r = 0; r < 4; ++r) {
          const int row = mi * 16 + lq * 4 + r;
          sm.e.c[d * 36 + row] = acc[mi][nt][r] + bias;
        }
    }
  }
  __syncthreads();

  const long long bidx = row0 >> 12;
  const int nbase = (int)(row0 & 4095);
  // ---- pack k: 32 rows x 128 cols, coalesced 16B stores ----
  {
    const int row = tid >> 3, c0 = (tid & 7) * 16;
    const u16* sp = &sm.e.kq[row * 136 + c0];
    u16* dst = kbuf + (row0 + row) * 128 + c0;
    *(uint4*)(dst) = *(const uint4*)(sp);
    *(uint4*)(dst + 8) = *(const uint4*)(sp + 8);
  }
  // ---- pack v^T: [d][N] bf16 ----
  {
    const int d = tid >> 1, nh = (tid & 1) * 16;
    const float* cp = &sm.e.c[d * 36 + nh];
    u16* dst = vt + (bidx * 128 + d) * 4096 + nbase + nh;
#pragma unroll
    for (int q = 0; q < 2; ++q) {
      uint4 p;
      p.x = pk2(cp[q * 8 + 0], cp[q * 8 + 1]);
      p.y = pk2(cp[q * 8 + 2], cp[q * 8 + 3]);
      p.z = pk2(cp[q * 8 + 4], cp[q * 8 + 5]);
      p.w = pk2(cp[q * 8 + 6], cp[q * 8 + 7]);
      *(uint4*)(dst + q * 8) = p;
    }
  }
}

// ---------------- K3: q-proj + dots + slot-softmax + P@v partials ----------
// grid 512 blocks (64 batches x 8 chunks), 256 thr. Wave handles 128 tokens.
__global__ __launch_bounds__(256) void k3_attn(
    const float* __restrict__ slots_in, const int* __restrict__ is_first, int iter,
    const float* __restrict__ lsg, const float* __restrict__ lsb,
    const u16* __restrict__ Wqt, const float* __restrict__ bq,
    const u16* __restrict__ kbuf, const u16* __restrict__ vt,
    float* __restrict__ updp, float* __restrict__ rsp) {
  const int ni = (*is_first) ? 3 : 2;
  if (iter >= ni) return;
  __shared__ alignas(16) u16 slns[16 * 136];
  __shared__ alignas(16) u16 qlds[16 * 136];
  __shared__ alignas(16) u16 plds[4][640];
  __shared__ alignas(16) float ures[4][16 * 128];
  __shared__ float rres[4][16];
  const int tid = threadIdx.x;
  const int wave = tid >> 6, lane = tid & 63;
  const int lq = lane >> 4, lm = lane & 15;
  const int b = blockIdx.x >> 3, chunk = blockIdx.x & 7;

  // LN(slots) by wave 0
  if (wave == 0) {
    const int s = lane >> 2, cc = (lane & 3) * 32;
    const float* sp = slots_in + ((long long)b * 16 + s) * 128 + cc;
    float x[32];
    float sum = 0.f, sq = 0.f;
#pragma unroll
    for (int j = 0; j < 32; ++j) { x[j] = sp[j]; sum += x[j]; sq += x[j] * x[j]; }
    sum += __shfl_xor(sum, 1); sum += __shfl_xor(sum, 2);
    sq  += __shfl_xor(sq, 1);  sq  += __shfl_xor(sq, 2);
    const float mu = sum * (1.f / 128.f);
    const float rstd = rsqrtf(sq * (1.f / 128.f) - mu * mu + LNEPS);
#pragma unroll
    for (int j = 0; j < 32; ++j) {
      const int c = cc + j;
      slns[s * 136 + c] = f2bf((x[j] - mu) * rstd * lsg[c] + lsb[c]);
    }
  }
  __syncthreads();
  // q = LN(slots) @ Wq + bq ; wave computes cols [wave*32, wave*32+32)
  {
    f32x4 qa0 = {0.f, 0.f, 0.f, 0.f}, qa1 = {0.f, 0.f, 0.f, 0.f};
#pragma unroll
    for (int ks = 0; ks < 4; ++ks) {
      const bf16x8 af = *(const bf16x8*)&slns[lm * 136 + ks * 32 + lq * 8];
      const bf16x8 b0 = *(const bf16x8*)&Wqt[(wave * 32 + lm) * 128 + ks * 32 + lq * 8];
      const bf16x8 b1 = *(const bf16x8*)&Wqt[(wave * 32 + 16 + lm) * 128 + ks * 32 + lq * 8];
      qa0 = mfma16(af, b0, qa0);
      qa1 = mfma16(af, b1, qa1);
    }
#pragma unroll
    for (int r = 0; r < 4; ++r) {
      const int s = lq * 4 + r;
      const int c0 = wave * 32 + lm, c1 = c0 + 16;
      qlds[s * 136 + c0] = f2bf(qa0[r] + bq[c0]);
      qlds[s * 136 + c1] = f2bf(qa1[r] + bq[c1]);
    }
  }
  __syncthreads();

  bf16x8 qf[4];
#pragma unroll
  for (int ks = 0; ks < 4; ++ks)
    qf[ks] = *(const bf16x8*)&qlds[lm * 136 + ks * 32 + lq * 8];

  float rs0 = 0.f, rs1 = 0.f, rs2 = 0.f, rs3 = 0.f;
  const f32x4 z4 = {0.f, 0.f, 0.f, 0.f};
  f32x4 uacc[8];
#pragma unroll
  for (int i = 0; i < 8; ++i) uacc[i] = z4;
  u16* pw = plds[wave];
  const int n0w = chunk * 512 + wave * 128;
  const u16* kb = kbuf + (long long)b * 4096 * 128;
  const u16* vb = vt + (long long)b * 128 * 4096;

  for (int g = 0; g < 4; ++g) {
    const int nb = n0w + g * 32;
#pragma unroll
    for (int sub = 0; sub < 2; ++sub) {
      f32x4 dot = z4;
      const u16* kr = kb + (long long)(nb + sub * 16 + lm) * 128 + lq * 8;
#pragma unroll
      for (int ks = 0; ks < 4; ++ks)
        dot = mfma16(qf[ks], *(const bf16x8*)&kr[ks * 32], dot);
      const float d0 = dot[0] * SCALE, d1 = dot[1] * SCALE;
      const float d2 = dot[2] * SCALE, d3 = dot[3] * SCALE;
      float m = fmaxf(fmaxf(d0, d1), fmaxf(d2, d3));
      m = fmaxf(m, __shfl_xor(m, 16));
      m = fmaxf(m, __shfl_xor(m, 32));
      const float e0 = __expf(d0 - m), e1 = __expf(d1 - m);
      const float e2 = __expf(d2 - m), e3 = __expf(d3 - m);
      float ss = e0 + e1 + e2 + e3;
      ss += __shfl_xor(ss, 16);
      ss += __shfl_xor(ss, 32);
      const float inv = 1.f / ss;
      const float p0 = e0 * inv + ATTN_EPS, p1 = e1 * inv + ATTN_EPS;
      const float p2 = e2 * inv + ATTN_EPS, p3 = e3 * inv + ATTN_EPS;
      rs0 += p0; rs1 += p1; rs2 += p2; rs3 += p3;
      const int nc = sub * 16 + lm;
      pw[(lq * 4 + 0) * 40 + nc] = f2bf(p0);
      pw[(lq * 4 + 1) * 40 + nc] = f2bf(p1);
      pw[(lq * 4 + 2) * 40 + nc] = f2bf(p2);
      pw[(lq * 4 + 3) * 40 + nc] = f2bf(p3);
    }
    const bf16x8 pa = *(const bf16x8*)&pw[lm * 40 + lq * 8];
    const u16* vr = vb + (long long)lm * 4096 + nb + lq * 8;
#pragma unroll
    for (int dt = 0; dt < 8; ++dt)
      uacc[dt] = mfma16(pa, *(const bf16x8*)&vr[(long long)dt * 16 * 4096], uacc[dt]);
  }
  // rowsum reduce across the 16 lanes of each quarter
#pragma unroll
  for (int msk = 1; msk < 16; msk <<= 1) {
    rs0 += __shfl_xor(rs0, msk); rs1 += __shfl_xor(rs1, msk);
    rs2 += __shfl_xor(rs2, msk); rs3 += __shfl_xor(rs3, msk);
  }
#pragma unroll
  for (int dt = 0; dt < 8; ++dt)
#pragma unroll
    for (int r = 0; r < 4; ++r)
      ures[wave][(lq * 4 + r) * 128 + dt * 16 + lm] = uacc[dt][r];
  if (lm == 0) {
    rres[wave][lq * 4 + 0] = rs0; rres[wave][lq * 4 + 1] = rs1;
    rres[wave][lq * 4 + 2] = rs2; rres[wave][lq * 4 + 3] = rs3;
  }
  __syncthreads();
  {
    const int e0 = tid * 8;
    float* dst = updp + (long long)(b * 8 + chunk) * 2048 + e0;
#pragma unroll
    for (int e = 0; e < 8; ++e)
      dst[e] = ures[0][e0 + e] + ures[1][e0 + e] + ures[2][e0 + e] + ures[3][e0 + e];
  }
  if (tid < 16)
    rsp[(b * 8 + chunk) * 16 + tid] =
        rres[0][tid] + rres[1][tid] + rres[2][tid] + rres[3][tid];
}

// ---------------- K4: reduce partials + GRU + MLP -> new slots -------------
// grid 64 blocks (batch), 256 thr.
__global__ __launch_bounds__(256) void k4_update(
    const float* __restrict__ slots_in, const int* __restrict__ is_first, int iter,
    const float* __restrict__ updp, const float* __restrict__ rsp,
    const u16* __restrict__ Wih, const u16* __restrict__ Whh,
    const float* __restrict__ bih, const float* __restrict__ bhh,
    const float* __restrict__ lmg, const float* __restrict__ lmb,
    const u16* __restrict__ W1t, const float* __restrict__ b1,
    const u16* __restrict__ W2t, const float* __restrict__ b2,
    float* __restrict__ slots_out, float* __restrict__ dout) {
  const int ni = (*is_first) ? 3 : 2;
  if (iter >= ni) return;
  const bool last = (iter == ni - 1);
  __shared__ float g_ih[16 * 392];
  __shared__ float g_hh[16 * 392];
  __shared__ alignas(16) float hsp[16 * 128];
  __shared__ float rsum[16];
  __shared__ alignas(16) u16 ubf[16 * 136];
  __shared__ alignas(16) u16 xbf[16 * 136];
  __shared__ alignas(16) u16 hidbf[16 * 520];
  const int tid = threadIdx.x;
  const int wave = tid >> 6, lane = tid & 63;
  const int lq = lane >> 4, lm = lane & 15;
  const int b = blockIdx.x;
  const int es = tid >> 4;         // slot row for this thread's 8 elems
  const int ej = (tid & 15) * 8;   // col start

  // slots_prev -> hsp (fp32) and xbf (bf16)
  {
    const float* sp = slots_in + (long long)b * 2048 + tid * 8;
    const float4 a = ((const float4*)sp)[0], c = ((const float4*)sp)[1];
    *(float4*)&hsp[tid * 8] = a;
    *(float4*)&hsp[tid * 8 + 4] = c;
    uint4 p;
    p.x = pk2(a.x, a.y);
    p.y = pk2(a.z, a.w);
    p.z = pk2(c.x, c.y);
    p.w = pk2(c.z, c.w);
    *(uint4*)&xbf[es * 136 + ej] = p;
  }
  if (tid < 16) {
    float s = 0.f;
    for (int p = 0; p < 8; ++p) s += rsp[(b * 8 + p) * 16 + tid];
    rsum[tid] = s;
  }
  __syncthreads();
  // reduce updates partials, normalize by rowsum -> ubf (bf16)
  {
    float acc[8];
#pragma unroll
    for (int e = 0; e < 8; ++e) acc[e] = 0.f;
    for (int p = 0; p < 8; ++p) {
      const float* src = updp + (long long)(b * 8 + p) * 2048 + tid * 8;
      const float4 x = ((const float4*)src)[0], y = ((const float4*)src)[1];
      acc[0] += x.x; acc[1] += x.y; acc[2] += x.z; acc[3] += x.w;
      acc[4] += y.x; acc[5] += y.y; acc[6] += y.z; acc[7] += y.w;
    }
    const float inv = 1.f / rsum[es];
    uint4 p;
    p.x = pk2(acc[0] * inv, acc[1] * inv);
    p.y = pk2(acc[2] * inv, acc[3] * inv);
    p.z = pk2(acc[4] * inv, acc[5] * inv);
    p.w = pk2(acc[6] * inv, acc[7] * inv);
    *(uint4*)&ubf[es * 136 + ej] = p;
  }
  __syncthreads();
  // gi = u @ Wih^T + bih ; gh = h @ Whh^T + bhh  (wave: cols wave*96..+96)
  {
    bf16x8 ua[4], ha[4];
#pragma unroll
    for (int ks = 0; ks < 4; ++ks) {
      ua[ks] = *(const bf16x8*)&ubf[lm * 136 + ks * 32 + lq * 8];
      ha[ks] = *(const bf16x8*)&xbf[lm * 136 + ks * 32 + lq * 8];
    }
    const f32x4 z4 = {0.f, 0.f, 0.f, 0.f};
    f32x4 gi[6], gh[6];
#pragma unroll
    for (int t = 0; t < 6; ++t) { gi[t] = z4; gh[t] = z4; }
#pragma unroll
    for (int ks = 0; ks < 4; ++ks)
#pragma unroll
      for (int t = 0; t < 6; ++t) {
        const int col = wave * 96 + t * 16 + lm;
        gi[t] = mfma16(ua[ks], *(const bf16x8*)&Wih[(long long)col * 128 + ks * 32 + lq * 8], gi[t]);
        gh[t] = mfma16(ha[ks], *(const bf16x8*)&Whh[(long long)col * 128 + ks * 32 + lq * 8], gh[t]);
      }
#pragma unroll
    for (int t = 0; t < 6; ++t)
#pragma unroll
      for (int r = 0; r < 4; ++r) {
        const int col = wave * 96 + t * 16 + lm, s = lq * 4 + r;
        g_ih[s * 392 + col] = gi[t][r] + bih[col];
        g_hh[s * 392 + col] = gh[t][r] + bhh[col];
      }
  }
  __syncthreads();
  // gates (elementwise), h overwrites hsp
  {
#pragma unroll
    for (int e = 0; e < 8; ++e) {
      const int j = ej + e;
      const float sr = g_ih[es * 392 + j] + g_hh[es * 392 + j];
      const float sz = g_ih[es * 392 + 128 + j] + g_hh[es * 392 + 128 + j];
      const float r = 1.f / (1.f + __expf(-sr));
      const float z = 1.f / (1.f + __expf(-sz));
      const float n = tanhf(g_ih[es * 392 + 256 + j] + r * g_hh[es * 392 + 256 + j]);
      hsp[es * 128 + j] = (1.f - z) * n + z * hsp[es * 128 + j];
    }
  }
  __syncthreads();
  // LN(h) -> xbf (wave 0)
  if (wave == 0) {
    const int s = lane >> 2, cc = (lane & 3) * 32;
    float x[32];
    float sum = 0.f, sq = 0.f;
#pragma unroll
    for (int j = 0; j < 32; ++j) {
      x[j] = hsp[s * 128 + cc + j]; sum += x[j]; sq += x[j] * x[j];
    }
    sum += __shfl_xor(sum, 1); sum += __shfl_xor(sum, 2);
    sq  += __shfl_xor(sq, 1);  sq  += __shfl_xor(sq, 2);
    const float mu = sum * (1.f / 128.f);
    const float rstd = rsqrtf(sq * (1.f / 128.f) - mu * mu + LNEPS);
#pragma unroll
    for (int j = 0; j < 32; ++j) {
      const int c = cc + j;
      xbf[s * 136 + c] = f2bf((x[j] - mu) * rstd * lmg[c] + lmb[c]);
    }
  }
  __syncthreads();
  // MLP1: hid = relu(LN(h) @ W1 + b1)   (wave: cols wave*128..+128)
  {
    bf16x8 xa[4];
#pragma unroll
    for (int ks = 0; ks < 4; ++ks)
      xa[ks] = *(const bf16x8*)&xbf[lm * 136 + ks * 32 + lq * 8];
    const f32x4 z4 = {0.f, 0.f, 0.f, 0.f};
    f32x4 m1[8];
#pragma unroll
    for (int t = 0; t < 8; ++t) m1[t] = z4;
#pragma unroll
    for (int ks = 0; ks < 4; ++ks)
#pragma unroll
      for (int t = 0; t < 8; ++t) {
        const int col = wave * 128 + t * 16 + lm;
        m1[t] = mfma16(xa[ks], *(const bf16x8*)&W1t[(long long)col * 128 + ks * 32 + lq * 8], m1[t]);
      }
#pragma unroll
    for (int t = 0; t < 8; ++t)
#pragma unroll
      for (int r = 0; r < 4; ++r) {
        const int col = wave * 128 + t * 16 + lm, s = lq * 4 + r;
        hidbf[s * 520 + col] = f2bf(fmaxf(m1[t][r] + b1[col], 0.f));
      }
  }
  __syncthreads();
  // MLP2 + residual: out = h + hid @ W2 + b2  (wave: cols wave*32..+32)
  {
    const f32x4 z4 = {0.f, 0.f, 0.f, 0.f};
    f32x4 m2a = z4, m2b = z4;
#pragma unroll
    for (int ks = 0; ks < 16; ++ks) {
      const bf16x8 xa = *(const bf16x8*)&hidbf[lm * 520 + ks * 32 + lq * 8];
      m2a = mfma16(xa, *(const bf16x8*)&W2t[(long long)(wave * 32 + lm) * 512 + ks * 32 + lq * 8], m2a);
      m2b = mfma16(xa, *(const bf16x8*)&W2t[(long long)(wave * 32 + 16 + lm) * 512 + ks * 32 + lq * 8], m2b);
    }
#pragma unroll
    for (int r = 0; r < 4; ++r) {
      const int s = lq * 4 + r;
      const int c0 = wave * 32 + lm, c1 = c0 + 16;
      const float o0 = m2a[r] + b2[c0] + hsp[s * 128 + c0];
      const float o1 = m2b[r] + b2[c1] + hsp[s * 128 + c1];
      float* o = slots_out + ((long long)b * 16 + s) * 128;
      o[c0] = o0; o[c1] = o1;
      if (last) {
        float* d = dout + ((long long)b * 16 + s) * 128;
        d[c0] = o0; d[c1] = o1;
      }
    }
  }
}

extern "C" void kernel_launch(void* const* d_in, const int* in_sizes, int n_in,
                              void* d_out, int out_size, void* d_ws, size_t ws_size,
                              hipStream_t stream) {
  (void)in_sizes; (void)n_in; (void)out_size; (void)ws_size;
  const float* feats    = (const float*)d_in[0];
  const float* slots0   = (const float*)d_in[1];
  const int*   is_first = (const int*)d_in[2];
  const float* ln_in_g  = (const float*)d_in[3];
  const float* ln_in_b  = (const float*)d_in[4];
  const float* ln_sl_g  = (const float*)d_in[5];
  const float* ln_sl_b  = (const float*)d_in[6];
  const float* ln_ml_g  = (const float*)d_in[7];
  const float* ln_ml_b  = (const float*)d_in[8];
  const float* Wq  = (const float*)d_in[9];
  const float* bq  = (const float*)d_in[10];
  const float* Wk  = (const float*)d_in[11];
  const float* bk  = (const float*)d_in[12];
  const float* Wv  = (const float*)d_in[13];
  const float* bv  = (const float*)d_in[14];
  const float* Wih_f = (const float*)d_in[15];
  const float* Whh_f = (const float*)d_in[16];
  const float* bih = (const float*)d_in[17];
  const float* bhh = (const float*)d_in[18];
  const float* W1  = (const float*)d_in[19];
  const float* b1  = (const float*)d_in[20];
  const float* W2  = (const float*)d_in[21];
  const float* b2  = (const float*)d_in[22];

  char* ws = (char*)d_ws;
  size_t off = 0;
  auto alloc = [&](size_t bytes) -> void* {
    void* p = ws + off;
    off = (off + bytes + 255) & ~(size_t)255;
    return p;
  };
  u16* kbuf   = (u16*)alloc((size_t)64 * 4096 * 128 * 2);
  u16* vt     = (u16*)alloc((size_t)64 * 4096 * 128 * 2);
  u16* Wcat   = (u16*)alloc((size_t)16 * 256 * 32 * 2);
  u16* Wqt    = (u16*)alloc((size_t)128 * 128 * 2);
  u16* Wih    = (u16*)alloc((size_t)384 * 128 * 2);
  u16* Whh    = (u16*)alloc((size_t)384 * 128 * 2);
  u16* W1t    = (u16*)alloc((size_t)512 * 128 * 2);
  u16* W2t    = (u16*)alloc((size_t)128 * 512 * 2);
  float* updp = (float*)alloc((size_t)64 * 8 * 2048 * 4);
  float* rsp  = (float*)alloc((size_t)64 * 8 * 16 * 4);
  float* slA  = (float*)alloc((size_t)64 * 2048 * 4);
  float* slB  = (float*)alloc((size_t)64 * 2048 * 4);

  // single fused weight-conversion launch (was 7 launches)
  cvt_all<<<1472, 256, 0, stream>>>(Wk, Wv, Wq, Wih_f, Whh_f, W1, W2,
                                    Wcat, Wqt, Wih, Whh, W1t, W2t);

  k1_lnproj<<<8192, 256, 0, stream>>>(feats, ln_in_g, ln_in_b, Wcat, bk, bv, kbuf, vt);

  float* bufs[2] = {slA, slB};
  for (int it = 0; it < 3; ++it) {
    const float* sin_ = (it == 0) ? slots0 : bufs[(it + 1) & 1];
    float* sout = bufs[it & 1];
    k3_attn<<<512, 256, 0, stream>>>(sin_, is_first, it, ln_sl_g, ln_sl_b, Wqt, bq,
                                     kbuf, vt, updp, rsp);
    k4_update<<<64, 256, 0, stream>>>(sin_, is_first, it, updp, rsp, Wih, Whh,
                                      bih, bhh, ln_ml_g, ln_ml_b, W1t, b1, W2t, b2,
                                      sout, (float*)d_out);
  }
}

// Round 14
// 387.208 us; speedup vs baseline: 1.3867x; 1.0183x over previous
//
#include <hip/hip_runtime.h>

typedef __attribute__((ext_vector_type(4))) float f32x4;
typedef __attribute__((ext_vector_type(8))) short bf16x8;
typedef unsigned short u16;

#define LNEPS 1e-3f
#define ATTN_EPS 1e-8f
#define SCALE 0.044194173824159216f  // 512^-0.5

__device__ __forceinline__ u16 f2bf(float f) {
  union { float f; unsigned u; } v; v.f = f;
  unsigned r = v.u + 0x7fffu + ((v.u >> 16) & 1u);
  return (u16)(r >> 16);
}
__device__ __forceinline__ float bf2f(unsigned u) {
  union { float f; unsigned u; } v; v.u = (u & 0xffffu) << 16; return v.f;
}
__device__ __forceinline__ f32x4 mfma16(bf16x8 a, bf16x8 b, f32x4 c) {
  return __builtin_amdgcn_mfma_f32_16x16x32_bf16(a, b, c, 0, 0, 0);
}
__device__ __forceinline__ unsigned pk2(float a, float b) {
  return (unsigned)f2bf(a) | ((unsigned)f2bf(b) << 16);
}

// ---------------- single fused weight-conversion kernel ----------------
__global__ void cvt_all(
    const float* __restrict__ Wk, const float* __restrict__ Wv,
    const float* __restrict__ Wq, const float* __restrict__ Wih_f,
    const float* __restrict__ Whh_f, const float* __restrict__ W1,
    const float* __restrict__ W2, u16* __restrict__ Wcat,
    u16* __restrict__ Wqt, u16* __restrict__ Wih, u16* __restrict__ Whh,
    u16* __restrict__ W1t, u16* __restrict__ W2t) {
  const int i = blockIdx.x * blockDim.x + threadIdx.x;
  if (i < 65536) {
    const int k = i >> 7, c = i & 127;
    Wcat[(k >> 5) * 8192 + c * 32 + (k & 31)] = f2bf(Wk[i]);
  } else if (i < 131072) {
    const int j = i - 65536;
    const int k = j >> 7, c = j & 127;
    Wcat[(k >> 5) * 8192 + (c + 128) * 32 + (k & 31)] = f2bf(Wv[j]);
  } else if (i < 147456) {
    const int j = i - 131072;
    const int r = j >> 7, c = j & 127;
    Wqt[c * 128 + r] = f2bf(Wq[j]);
  } else if (i < 196608) {
    const int j = i - 147456;
    Wih[j] = f2bf(Wih_f[j]);
  } else if (i < 245760) {
    const int j = i - 196608;
    Whh[j] = f2bf(Whh_f[j]);
  } else if (i < 311296) {
    const int j = i - 245760;
    const int r = j / 512, c = j - r * 512;
    W1t[c * 128 + r] = f2bf(W1[j]);
  } else if (i < 376832) {
    const int j = i - 311296;
    const int r = j >> 7, c = j & 127;
    W2t[c * 512 + r] = f2bf(W2[j]);
  }
}

// ---------------- K1: LN(features) -> k,v projections (r9/r13 champion) ---
__global__ __launch_bounds__(256, 4) void k1_lnproj(
    const float* __restrict__ feats, const float* __restrict__ lng,
    const float* __restrict__ lnb, const u16* __restrict__ Wcat,
    const float* __restrict__ bk, const float* __restrict__ bv,
    u16* __restrict__ kbuf, u16* __restrict__ vt) {
  __shared__ alignas(16) union {
    u16 a[32 * 512];                                    // 32768 B (GEMM A)
    struct { u16 kq[32 * 136]; float c[128 * 36]; } e;  // 8704+18432 B
  } sm;
  const int tid = threadIdx.x;
  const int wave = tid >> 6, lane = tid & 63;
  const int lq = lane >> 4, lm = lane & 15;
  const long long row0 = (long long)blockIdx.x * 32;

  const float4 g0 = *(const float4*)&lng[lane * 8];
  const float4 g1 = *(const float4*)&lng[lane * 8 + 4];
  const float4 bb0 = *(const float4*)&lnb[lane * 8];
  const float4 bb1 = *(const float4*)&lnb[lane * 8 + 4];

  // ---- phase 1: load 8 rows/wave + butterfly stats + LN in regs ----
  {
    const float* base = feats + (row0 + wave * 8) * 512 + lane * 8;
    float4 x0[8], x1[8];
#pragma unroll
    for (int i = 0; i < 8; ++i) {
      x0[i] = ((const float4*)(base + i * 512))[0];
      x1[i] = ((const float4*)(base + i * 512))[1];
    }
#pragma unroll
    for (int i = 0; i < 8; ++i) {
      const int r = wave * 8 + i;
      float s = (x0[i].x + x0[i].y) + (x0[i].z + x0[i].w) +
                (x1[i].x + x1[i].y) + (x1[i].z + x1[i].w);
      float q = x0[i].x * x0[i].x + x0[i].y * x0[i].y + x0[i].z * x0[i].z +
                x0[i].w * x0[i].w + x1[i].x * x1[i].x + x1[i].y * x1[i].y +
                x1[i].z * x1[i].z + x1[i].w * x1[i].w;
#pragma unroll
      for (int m = 1; m < 64; m <<= 1) {
        s += __shfl_xor(s, m);
        q += __shfl_xor(q, m);
      }
      const float mu = s * (1.f / 512.f);
      const float rstd = rsqrtf(q * (1.f / 512.f) - mu * mu + LNEPS);
      const float y0 = (x0[i].x - mu) * rstd * g0.x + bb0.x;
      const float y1 = (x0[i].y - mu) * rstd * g0.y + bb0.y;
      const float y2 = (x0[i].z - mu) * rstd * g0.z + bb0.z;
      const float y3 = (x0[i].w - mu) * rstd * g0.w + bb0.w;
      const float y4 = (x1[i].x - mu) * rstd * g1.x + bb1.x;
      const float y5 = (x1[i].y - mu) * rstd * g1.y + bb1.y;
      const float y6 = (x1[i].z - mu) * rstd * g1.z + bb1.z;
      const float y7 = (x1[i].w - mu) * rstd * g1.w + bb1.w;
      uint4 w;
      w.x = pk2(y0, y1);
      w.y = pk2(y2, y3);
      w.z = pk2(y4, y5);
      w.w = pk2(y6, y7);
      *(uint4*)((char*)sm.a + r * 1024 + ((lane * 16) ^ ((r & 7) << 4))) = w;
    }
  }
  __syncthreads();

  // ---- GEMM: wave = col-quarter cq; rows 0..31 (2 m-tiles) ----
  const int cq = wave;
  f32x4 acc[2][4];
  {
    const f32x4 z4 = {0.f, 0.f, 0.f, 0.f};
#pragma unroll
    for (int m = 0; m < 2; ++m)
#pragma unroll
      for (int n = 0; n < 4; ++n) acc[m][n] = z4;
  }
  const u16* wb = Wcat + (cq * 64 + lm) * 32 + lq * 8;  // k-slab base
#pragma unroll 4
  for (int ks = 0; ks < 16; ++ks) {
    bf16x8 a[2], b[4];
#pragma unroll
    for (int mi = 0; mi < 2; ++mi) {
      const int row = mi * 16 + lm;
      a[mi] = *(const bf16x8*)((const char*)sm.a + row * 1024 +
                               ((ks * 64 + lq * 16) ^ ((row & 7) << 4)));
    }
#pragma unroll
    for (int nt = 0; nt < 4; ++nt)
      b[nt] = *(const bf16x8*)&wb[ks * 8192 + nt * 512];
#pragma unroll
    for (int mi = 0; mi < 2; ++mi)
#pragma unroll
      for (int nt = 0; nt < 4; ++nt)
        acc[mi][nt] = mfma16(a[mi], b[nt], acc[mi][nt]);
  }
  __syncthreads();  // A-tile dead; union becomes epilogue staging

  // ---- epilogue staging ----
  if (cq < 2) {
#pragma unroll
    for (int nt = 0; nt < 4; ++nt) {
      const int col = cq * 64 + nt * 16 + lm;
      const float bias = bk[col];
#pragma unroll
      for (int mi = 0; mi < 2; ++mi)
#pragma unroll
        for (int r = 0; r < 4; ++r) {
          const int row = mi * 16 + lq * 4 + r;
          sm.e.kq[row * 136 + col] = f2bf(acc[mi][nt][r] + bias);
        }
    }
  } else {
#pragma unroll
    for (int nt = 0; nt < 4; ++nt) {
      const int d = (cq - 2) * 64 + nt * 16 + lm;
      const float bias = bv[d];
#pragma unroll
      for (int mi = 0; mi < 2; ++mi)
#pragma unroll
        for (int r = 0; r < 4; ++r) {
          const int row = mi * 16 + lq * 4 + r;
          sm.e.c[d * 36 + row] = acc[mi][nt][r] + bias;
        }
    }
  }
  __syncthreads();

  const long long bidx = row0 >> 12;
  const int nbase = (int)(row0 & 4095);
  // ---- pack k ----
  {
    const int row = tid >> 3, c0 = (tid & 7) * 16;
    const u16* sp = &sm.e.kq[row * 136 + c0];
    u16* dst = kbuf + (row0 + row) * 128 + c0;
    *(uint4*)(dst) = *(const uint4*)(sp);
    *(uint4*)(dst + 8) = *(const uint4*)(sp + 8);
  }
  // ---- pack v^T ----
  {
    const int d = tid >> 1, nh = (tid & 1) * 16;
    const float* cp = &sm.e.c[d * 36 + nh];
    u16* dst = vt + (bidx * 128 + d) * 4096 + nbase + nh;
#pragma unroll
    for (int q = 0; q < 2; ++q) {
      uint4 p;
      p.x = pk2(cp[q * 8 + 0], cp[q * 8 + 1]);
      p.y = pk2(cp[q * 8 + 2], cp[q * 8 + 3]);
      p.z = pk2(cp[q * 8 + 4], cp[q * 8 + 5]);
      p.w = pk2(cp[q * 8 + 6], cp[q * 8 + 7]);
      *(uint4*)(dst + q * 8) = p;
    }
  }
}

// ---------------- K3: q-proj + dots + slot-softmax + P@v partials ----------
// grid 1024 blocks (64 batches x 16 chunks), 256 thr. Wave handles 64 tokens.
// (chunks 8->16: 4 blocks/CU residency for cross-block latency overlap)
__global__ __launch_bounds__(256) void k3_attn(
    const float* __restrict__ slots_in, const int* __restrict__ is_first, int iter,
    const float* __restrict__ lsg, const float* __restrict__ lsb,
    const u16* __restrict__ Wqt, const float* __restrict__ bq,
    const u16* __restrict__ kbuf, const u16* __restrict__ vt,
    float* __restrict__ updp, float* __restrict__ rsp) {
  const int ni = (*is_first) ? 3 : 2;
  if (iter >= ni) return;
  __shared__ alignas(16) u16 slns[16 * 136];
  __shared__ alignas(16) u16 qlds[16 * 136];
  __shared__ alignas(16) u16 plds[4][640];
  __shared__ alignas(16) float ures[4][16 * 128];
  __shared__ float rres[4][16];
  const int tid = threadIdx.x;
  const int wave = tid >> 6, lane = tid & 63;
  const int lq = lane >> 4, lm = lane & 15;
  const int b = blockIdx.x >> 4, chunk = blockIdx.x & 15;

  // LN(slots) by wave 0
  if (wave == 0) {
    const int s = lane >> 2, cc = (lane & 3) * 32;
    const float* sp = slots_in + ((long long)b * 16 + s) * 128 + cc;
    float x[32];
    float sum = 0.f, sq = 0.f;
#pragma unroll
    for (int j = 0; j < 32; ++j) { x[j] = sp[j]; sum += x[j]; sq += x[j] * x[j]; }
    sum += __shfl_xor(sum, 1); sum += __shfl_xor(sum, 2);
    sq  += __shfl_xor(sq, 1);  sq  += __shfl_xor(sq, 2);
    const float mu = sum * (1.f / 128.f);
    const float rstd = rsqrtf(sq * (1.f / 128.f) - mu * mu + LNEPS);
#pragma unroll
    for (int j = 0; j < 32; ++j) {
      const int c = cc + j;
      slns[s * 136 + c] = f2bf((x[j] - mu) * rstd * lsg[c] + lsb[c]);
    }
  }
  __syncthreads();
  // q = LN(slots) @ Wq + bq ; wave computes cols [wave*32, wave*32+32)
  {
    f32x4 qa0 = {0.f, 0.f, 0.f, 0.f}, qa1 = {0.f, 0.f, 0.f, 0.f};
#pragma unroll
    for (int ks = 0; ks < 4; ++ks) {
      const bf16x8 af = *(const bf16x8*)&slns[lm * 136 + ks * 32 + lq * 8];
      const bf16x8 b0 = *(const bf16x8*)&Wqt[(wave * 32 + lm) * 128 + ks * 32 + lq * 8];
      const bf16x8 b1 = *(const bf16x8*)&Wqt[(wave * 32 + 16 + lm) * 128 + ks * 32 + lq * 8];
      qa0 = mfma16(af, b0, qa0);
      qa1 = mfma16(af, b1, qa1);
    }
#pragma unroll
    for (int r = 0; r < 4; ++r) {
      const int s = lq * 4 + r;
      const int c0 = wave * 32 + lm, c1 = c0 + 16;
      qlds[s * 136 + c0] = f2bf(qa0[r] + bq[c0]);
      qlds[s * 136 + c1] = f2bf(qa1[r] + bq[c1]);
    }
  }
  __syncthreads();

  bf16x8 qf[4];
#pragma unroll
  for (int ks = 0; ks < 4; ++ks)
    qf[ks] = *(const bf16x8*)&qlds[lm * 136 + ks * 32 + lq * 8];

  float rs0 = 0.f, rs1 = 0.f, rs2 = 0.f, rs3 = 0.f;
  const f32x4 z4 = {0.f, 0.f, 0.f, 0.f};
  f32x4 uacc[8];
#pragma unroll
  for (int i = 0; i < 8; ++i) uacc[i] = z4;
  u16* pw = plds[wave];
  const int n0w = chunk * 256 + wave * 64;
  const u16* kb = kbuf + (long long)b * 4096 * 128;
  const u16* vb = vt + (long long)b * 128 * 4096;

  for (int g = 0; g < 2; ++g) {
    const int nb = n0w + g * 32;
#pragma unroll
    for (int sub = 0; sub < 2; ++sub) {
      f32x4 dot = z4;
      const u16* kr = kb + (long long)(nb + sub * 16 + lm) * 128 + lq * 8;
#pragma unroll
      for (int ks = 0; ks < 4; ++ks)
        dot = mfma16(qf[ks], *(const bf16x8*)&kr[ks * 32], dot);
      const float d0 = dot[0] * SCALE, d1 = dot[1] * SCALE;
      const float d2 = dot[2] * SCALE, d3 = dot[3] * SCALE;
      float m = fmaxf(fmaxf(d0, d1), fmaxf(d2, d3));
      m = fmaxf(m, __shfl_xor(m, 16));
      m = fmaxf(m, __shfl_xor(m, 32));
      const float e0 = __expf(d0 - m), e1 = __expf(d1 - m);
      const float e2 = __expf(d2 - m), e3 = __expf(d3 - m);
      float ss = e0 + e1 + e2 + e3;
      ss += __shfl_xor(ss, 16);
      ss += __shfl_xor(ss, 32);
      const float inv = 1.f / ss;
      const float p0 = e0 * inv + ATTN_EPS, p1 = e1 * inv + ATTN_EPS;
      const float p2 = e2 * inv + ATTN_EPS, p3 = e3 * inv + ATTN_EPS;
      rs0 += p0; rs1 += p1; rs2 += p2; rs3 += p3;
      const int nc = sub * 16 + lm;
      pw[(lq * 4 + 0) * 40 + nc] = f2bf(p0);
      pw[(lq * 4 + 1) * 40 + nc] = f2bf(p1);
      pw[(lq * 4 + 2) * 40 + nc] = f2bf(p2);
      pw[(lq * 4 + 3) * 40 + nc] = f2bf(p3);
    }
    const bf16x8 pa = *(const bf16x8*)&pw[lm * 40 + lq * 8];
    const u16* vr = vb + (long long)lm * 4096 + nb + lq * 8;
#pragma unroll
    for (int dt = 0; dt < 8; ++dt)
      uacc[dt] = mfma16(pa, *(const bf16x8*)&vr[(long long)dt * 16 * 4096], uacc[dt]);
  }
  // rowsum reduce across the 16 lanes of each quarter
#pragma unroll
  for (int msk = 1; msk < 16; msk <<= 1) {
    rs0 += __shfl_xor(rs0, msk); rs1 += __shfl_xor(rs1, msk);
    rs2 += __shfl_xor(rs2, msk); rs3 += __shfl_xor(rs3, msk);
  }
#pragma unroll
  for (int dt = 0; dt < 8; ++dt)
#pragma unroll
    for (int r = 0; r < 4; ++r)
      ures[wave][(lq * 4 + r) * 128 + dt * 16 + lm] = uacc[dt][r];
  if (lm == 0) {
    rres[wave][lq * 4 + 0] = rs0; rres[wave][lq * 4 + 1] = rs1;
    rres[wave][lq * 4 + 2] = rs2; rres[wave][lq * 4 + 3] = rs3;
  }
  __syncthreads();
  {
    const int e0 = tid * 8;
    float* dst = updp + (long long)(b * 16 + chunk) * 2048 + e0;
#pragma unroll
    for (int e = 0; e < 8; ++e)
      dst[e] = ures[0][e0 + e] + ures[1][e0 + e] + ures[2][e0 + e] + ures[3][e0 + e];
  }
  if (tid < 16)
    rsp[(b * 16 + chunk) * 16 + tid] =
        rres[0][tid] + rres[1][tid] + rres[2][tid] + rres[3][tid];
}

// ---------------- K4: reduce partials + GRU + MLP -> new slots -------------
// grid 64 blocks (batch), 256 thr. (16 partials now)
__global__ __launch_bounds__(256) void k4_update(
    const float* __restrict__ slots_in, const int* __restrict__ is_first, int iter,
    const float* __restrict__ updp, const float* __restrict__ rsp,
    const u16* __restrict__ Wih, const u16* __restrict__ Whh,
    const float* __restrict__ bih, const float* __restrict__ bhh,
    const float* __restrict__ lmg, const float* __restrict__ lmb,
    const u16* __restrict__ W1t, const float* __restrict__ b1,
    const u16* __restrict__ W2t, const float* __restrict__ b2,
    float* __restrict__ slots_out, float* __restrict__ dout) {
  const int ni = (*is_first) ? 3 : 2;
  if (iter >= ni) return;
  const bool last = (iter == ni - 1);
  __shared__ float g_ih[16 * 392];
  __shared__ float g_hh[16 * 392];
  __shared__ alignas(16) float hsp[16 * 128];
  __shared__ float rsum[16];
  __shared__ alignas(16) u16 ubf[16 * 136];
  __shared__ alignas(16) u16 xbf[16 * 136];
  __shared__ alignas(16) u16 hidbf[16 * 520];
  const int tid = threadIdx.x;
  const int wave = tid >> 6, lane = tid & 63;
  const int lq = lane >> 4, lm = lane & 15;
  const int b = blockIdx.x;
  const int es = tid >> 4;         // slot row for this thread's 8 elems
  const int ej = (tid & 15) * 8;   // col start

  // slots_prev -> hsp (fp32) and xbf (bf16)
  {
    const float* sp = slots_in + (long long)b * 2048 + tid * 8;
    const float4 a = ((const float4*)sp)[0], c = ((const float4*)sp)[1];
    *(float4*)&hsp[tid * 8] = a;
    *(float4*)&hsp[tid * 8 + 4] = c;
    uint4 p;
    p.x = pk2(a.x, a.y);
    p.y = pk2(a.z, a.w);
    p.z = pk2(c.x, c.y);
    p.w = pk2(c.z, c.w);
    *(uint4*)&xbf[es * 136 + ej] = p;
  }
  if (tid < 16) {
    float s = 0.f;
    for (int p = 0; p < 16; ++p) s += rsp[(b * 16 + p) * 16 + tid];
    rsum[tid] = s;
  }
  __syncthreads();
  // reduce updates partials, normalize by rowsum -> ubf (bf16)
  {
    float acc[8];
#pragma unroll
    for (int e = 0; e < 8; ++e) acc[e] = 0.f;
    for (int p = 0; p < 16; ++p) {
      const float* src = updp + (long long)(b * 16 + p) * 2048 + tid * 8;
      const float4 x = ((const float4*)src)[0], y = ((const float4*)src)[1];
      acc[0] += x.x; acc[1] += x.y; acc[2] += x.z; acc[3] += x.w;
      acc[4] += y.x; acc[5] += y.y; acc[6] += y.z; acc[7] += y.w;
    }
    const float inv = 1.f / rsum[es];
    uint4 p;
    p.x = pk2(acc[0] * inv, acc[1] * inv);
    p.y = pk2(acc[2] * inv, acc[3] * inv);
    p.z = pk2(acc[4] * inv, acc[5] * inv);
    p.w = pk2(acc[6] * inv, acc[7] * inv);
    *(uint4*)&ubf[es * 136 + ej] = p;
  }
  __syncthreads();
  // gi = u @ Wih^T + bih ; gh = h @ Whh^T + bhh  (wave: cols wave*96..+96)
  {
    bf16x8 ua[4], ha[4];
#pragma unroll
    for (int ks = 0; ks < 4; ++ks) {
      ua[ks] = *(const bf16x8*)&ubf[lm * 136 + ks * 32 + lq * 8];
      ha[ks] = *(const bf16x8*)&xbf[lm * 136 + ks * 32 + lq * 8];
    }
    const f32x4 z4 = {0.f, 0.f, 0.f, 0.f};
    f32x4 gi[6], gh[6];
#pragma unroll
    for (int t = 0; t < 6; ++t) { gi[t] = z4; gh[t] = z4; }
#pragma unroll
    for (int ks = 0; ks < 4; ++ks)
#pragma unroll
      for (int t = 0; t < 6; ++t) {
        const int col = wave * 96 + t * 16 + lm;
        gi[t] = mfma16(ua[ks], *(const bf16x8*)&Wih[(long long)col * 128 + ks * 32 + lq * 8], gi[t]);
        gh[t] = mfma16(ha[ks], *(const bf16x8*)&Whh[(long long)col * 128 + ks * 32 + lq * 8], gh[t]);
      }
#pragma unroll
    for (int t = 0; t < 6; ++t)
#pragma unroll
      for (int r = 0; r < 4; ++r) {
        const int col = wave * 96 + t * 16 + lm, s = lq * 4 + r;
        g_ih[s * 392 + col] = gi[t][r] + bih[col];
        g_hh[s * 392 + col] = gh[t][r] + bhh[col];
      }
  }
  __syncthreads();
  // gates (elementwise), h overwrites hsp
  {
#pragma unroll
    for (int e = 0; e < 8; ++e) {
      const int j = ej + e;
      const float sr = g_ih[es * 392 + j] + g_hh[es * 392 + j];
      const float sz = g_ih[es * 392 + 128 + j] + g_hh[es * 392 + 128 + j];
      const float r = 1.f / (1.f + __expf(-sr));
      const float z = 1.f / (1.f + __expf(-sz));
      const float n = tanhf(g_ih[es * 392 + 256 + j] + r * g_hh[es * 392 + 256 + j]);
      hsp[es * 128 + j] = (1.f - z) * n + z * hsp[es * 128 + j];
    }
  }
  __syncthreads();
  // LN(h) -> xbf (wave 0)
  if (wave == 0) {
    const int s = lane >> 2, cc = (lane & 3) * 32;
    float x[32];
    float sum = 0.f, sq = 0.f;
#pragma unroll
    for (int j = 0; j < 32; ++j) {
      x[j] = hsp[s * 128 + cc + j]; sum += x[j]; sq += x[j] * x[j];
    }
    sum += __shfl_xor(sum, 1); sum += __shfl_xor(sum, 2);
    sq  += __shfl_xor(sq, 1);  sq  += __shfl_xor(sq, 2);
    const float mu = sum * (1.f / 128.f);
    const float rstd = rsqrtf(sq * (1.f / 128.f) - mu * mu + LNEPS);
#pragma unroll
    for (int j = 0; j < 32; ++j) {
      const int c = cc + j;
      xbf[s * 136 + c] = f2bf((x[j] - mu) * rstd * lmg[c] + lmb[c]);
    }
  }
  __syncthreads();
  // MLP1: hid = relu(LN(h) @ W1 + b1)   (wave: cols wave*128..+128)
  {
    bf16x8 xa[4];
#pragma unroll
    for (int ks = 0; ks < 4; ++ks)
      xa[ks] = *(const bf16x8*)&xbf[lm * 136 + ks * 32 + lq * 8];
    const f32x4 z4 = {0.f, 0.f, 0.f, 0.f};
    f32x4 m1[8];
#pragma unroll
    for (int t = 0; t < 8; ++t) m1[t] = z4;
#pragma unroll
    for (int ks = 0; ks < 4; ++ks)
#pragma unroll
      for (int t = 0; t < 8; ++t) {
        const int col = wave * 128 + t * 16 + lm;
        m1[t] = mfma16(xa[ks], *(const bf16x8*)&W1t[(long long)col * 128 + ks * 32 + lq * 8], m1[t]);
      }
#pragma unroll
    for (int t = 0; t < 8; ++t)
#pragma unroll
      for (int r = 0; r < 4; ++r) {
        const int col = wave * 128 + t * 16 + lm, s = lq * 4 + r;
        hidbf[s * 520 + col] = f2bf(fmaxf(m1[t][r] + b1[col], 0.f));
      }
  }
  __syncthreads();
  // MLP2 + residual: out = h + hid @ W2 + b2  (wave: cols wave*32..+32)
  {
    const f32x4 z4 = {0.f, 0.f, 0.f, 0.f};
    f32x4 m2a = z4, m2b = z4;
#pragma unroll
    for (int ks = 0; ks < 16; ++ks) {
      const bf16x8 xa = *(const bf16x8*)&hidbf[lm * 520 + ks * 32 + lq * 8];
      m2a = mfma16(xa, *(const bf16x8*)&W2t[(long long)(wave * 32 + lm) * 512 + ks * 32 + lq * 8], m2a);
      m2b = mfma16(xa, *(const bf16x8*)&W2t[(long long)(wave * 32 + 16 + lm) * 512 + ks * 32 + lq * 8], m2b);
    }
#pragma unroll
    for (int r = 0; r < 4; ++r) {
      const int s = lq * 4 + r;
      const int c0 = wave * 32 + lm, c1 = c0 + 16;
      const float o0 = m2a[r] + b2[c0] + hsp[s * 128 + c0];
      const float o1 = m2b[r] + b2[c1] + hsp[s * 128 + c1];
      float* o = slots_out + ((long long)b * 16 + s) * 128;
      o[c0] = o0; o[c1] = o1;
      if (last) {
        float* d = dout + ((long long)b * 16 + s) * 128;
        d[c0] = o0; d[c1] = o1;
      }
    }
  }
}

extern "C" void kernel_launch(void* const* d_in, const int* in_sizes, int n_in,
                              void* d_out, int out_size, void* d_ws, size_t ws_size,
                              hipStream_t stream) {
  (void)in_sizes; (void)n_in; (void)out_size; (void)ws_size;
  const float* feats    = (const float*)d_in[0];
  const float* slots0   = (const float*)d_in[1];
  const int*   is_first = (const int*)d_in[2];
  const float* ln_in_g  = (const float*)d_in[3];
  const float* ln_in_b  = (const float*)d_in[4];
  const float* ln_sl_g  = (const float*)d_in[5];
  const float* ln_sl_b  = (const float*)d_in[6];
  const float* ln_ml_g  = (const float*)d_in[7];
  const float* ln_ml_b  = (const float*)d_in[8];
  const float* Wq  = (const float*)d_in[9];
  const float* bq  = (const float*)d_in[10];
  const float* Wk  = (const float*)d_in[11];
  const float* bk  = (const float*)d_in[12];
  const float* Wv  = (const float*)d_in[13];
  const float* bv  = (const float*)d_in[14];
  const float* Wih_f = (const float*)d_in[15];
  const float* Whh_f = (const float*)d_in[16];
  const float* bih = (const float*)d_in[17];
  const float* bhh = (const float*)d_in[18];
  const float* W1  = (const float*)d_in[19];
  const float* b1  = (const float*)d_in[20];
  const float* W2  = (const float*)d_in[21];
  const float* b2  = (const float*)d_in[22];

  char* ws = (char*)d_ws;
  size_t off = 0;
  auto alloc = [&](size_t bytes) -> void* {
    void* p = ws + off;
    off = (off + bytes + 255) & ~(size_t)255;
    return p;
  };
  u16* kbuf   = (u16*)alloc((size_t)64 * 4096 * 128 * 2);
  u16* vt     = (u16*)alloc((size_t)64 * 4096 * 128 * 2);
  u16* Wcat   = (u16*)alloc((size_t)16 * 256 * 32 * 2);
  u16* Wqt    = (u16*)alloc((size_t)128 * 128 * 2);
  u16* Wih    = (u16*)alloc((size_t)384 * 128 * 2);
  u16* Whh    = (u16*)alloc((size_t)384 * 128 * 2);
  u16* W1t    = (u16*)alloc((size_t)512 * 128 * 2);
  u16* W2t    = (u16*)alloc((size_t)128 * 512 * 2);
  float* updp = (float*)alloc((size_t)64 * 16 * 2048 * 4);
  float* rsp  = (float*)alloc((size_t)64 * 16 * 16 * 4);
  float* slA  = (float*)alloc((size_t)64 * 2048 * 4);
  float* slB  = (float*)alloc((size_t)64 * 2048 * 4);

  // single fused weight-conversion launch
  cvt_all<<<1472, 256, 0, stream>>>(Wk, Wv, Wq, Wih_f, Whh_f, W1, W2,
                                    Wcat, Wqt, Wih, Whh, W1t, W2t);

  k1_lnproj<<<8192, 256, 0, stream>>>(feats, ln_in_g, ln_in_b, Wcat, bk, bv, kbuf, vt);

  float* bufs[2] = {slA, slB};
  for (int it = 0; it < 3; ++it) {
    const float* sin_ = (it == 0) ? slots0 : bufs[(it + 1) & 1];
    float* sout = bufs[it & 1];
    k3_attn<<<1024, 256, 0, stream>>>(sin_, is_first, it, ln_sl_g, ln_sl_b, Wqt, bq,
                                      kbuf, vt, updp, rsp);
    k4_update<<<64, 256, 0, stream>>>(sin_, is_first, it, updp, rsp, Wih, Whh,
                                      bih, bhh, ln_ml_g, ln_ml_b, W1t, b1, W2t, b2,
                                      sout, (float*)d_out);
  }
}